// Round 4
// baseline (512.080 us; speedup 1.0000x reference)
//
#include <hip/hip_runtime.h>
#include <hip/hip_bf16.h>

typedef unsigned short u16;
typedef unsigned int u32;
typedef __attribute__((ext_vector_type(8))) short short8;
typedef __attribute__((ext_vector_type(4))) float f32x4;
typedef __attribute__((ext_vector_type(2))) float f32x2;

#define HD 128
#define ETILE 8192

__device__ inline float b2f(u16 u){ u32 v = ((u32)u) << 16; return __uint_as_float(v); }
__device__ inline u16 f2b(float f){
  u32 u = __float_as_uint(f);
  u32 r = (u + 0x7fffu + ((u >> 16) & 1u)) >> 16;
  return (u16)r;
}
// packed f32x2 -> bf16x2 via HW convert
__device__ inline u32 pack2(float a, float b){
  __hip_bfloat162 h = __float22bfloat162_rn(make_float2(a, b));
  union { __hip_bfloat162 h; u32 u; } c; c.h = h; return c.u;
}
__device__ inline float lo2f(u32 w){ return b2f((u16)(w & 0xffff)); }
__device__ inline float hi2f(u32 w){ return b2f((u16)(w >> 16)); }
__device__ inline float eluf(float x){ return x > 0.f ? x : __expf(x) - 1.f; }
__device__ inline float reluf(float x){ return x > 0.f ? x : 0.f; }
__device__ inline float sane(float x){
  if (!(x == x)) return 0.f;
  return fminf(fmaxf(x, -1e30f), 1e30f);
}
// monotone float<->u32 encoding for atomicMax on signed floats
__device__ inline u32 fenc(float f){ u32 u = __float_as_uint(f); return (u & 0x80000000u) ? ~u : (u | 0x80000000u); }
__device__ inline float fdec(u32 u){ return __uint_as_float((u & 0x80000000u) ? (u & 0x7fffffffu) : ~u); }
// async 16B global->LDS
__device__ __forceinline__ void async16(const u16* g, u16* l){
  __builtin_amdgcn_global_load_lds((const __attribute__((address_space(1))) void*)g,
                                   (__attribute__((address_space(3))) void*)l, 16, 0, 0);
}

// ---------------- small precompute ----------------
__global__ void k_small(const float* __restrict__ na_a, const float* __restrict__ sc_a,
                        const float* __restrict__ la_a, const float* __restrict__ gatW,
                        const float* __restrict__ gat_as, const float* __restrict__ gat_ad,
                        const float* __restrict__ gin_eps, float* __restrict__ sm,
                        u32* __restrict__ maxs)
{
  int t = threadIdx.x;
  if (t < 3) maxs[t] = 0u;
  if (t == 0){
    for (int l = 0; l < 3; l++){
      float a[4]; float mx = -1e30f;
      for (int i = 0; i < 4; i++){ a[i] = na_a[l*4+i]; mx = fmaxf(mx, a[i]); }
      float ssum = 0.f;
      for (int i = 0; i < 4; i++){ a[i] = __expf(a[i]-mx); ssum += a[i]; }
      for (int i = 0; i < 4; i++) sm[l*4+i] = a[i]/ssum;
    }
    for (int r = 0; r < 2; r++){
      float a0 = sc_a[r*2], a1 = sc_a[r*2+1];
      float mx = fmaxf(a0,a1);
      float e0 = __expf(a0-mx), e1 = __expf(a1-mx);
      sm[12+r] = e1/(e0+e1);
    }
    {
      float a0=la_a[0], a1=la_a[1], a2=la_a[2];
      float mx = fmaxf(fmaxf(a0,a1),a2);
      float e0=__expf(a0-mx), e1=__expf(a1-mx), e2=__expf(a2-mx);
      float ssum = e0+e1+e2;
      sm[14]=e0/ssum; sm[15]=e1/ssum; sm[16]=e2/ssum;
    }
    for (int l=0;l<3;l++) sm[17+l] = 1.f + gin_eps[l];
  }
  if (t < 128){
    for (int l=0;l<3;l++){
      float a1=0.f, a2=0.f;
      for (int k=0;k<128;k++){
        float wv = gatW[l*16384 + k*128 + t];
        a1 = fmaf(wv, gat_as[l*128+k], a1);
        a2 = fmaf(wv, gat_ad[l*128+k], a2);
      }
      sm[32  + l*128 + t] = a1;
      sm[416 + l*128 + t] = a2;
    }
  }
}

// -------- weight pre-conversion f32 -> bf16, PRE-SWIZZLED chunk order -------
__device__ __forceinline__ uint4 cvt8(const float* __restrict__ p){
  float4 v0 = *(const float4*)p;
  float4 v1 = *(const float4*)(p + 4);
  uint4 o;
  o.x = pack2(v0.x, v0.y);
  o.y = pack2(v0.z, v0.w);
  o.z = pack2(v1.x, v1.y);
  o.w = pack2(v1.z, v1.w);
  return o;
}
__global__ void k_wcvt(const float* __restrict__ lin1W, const float* __restrict__ gcnW,
                       const float* __restrict__ Ws, const float* __restrict__ Wn,
                       const float* __restrict__ ginW, const float* __restrict__ gatW,
                       u16* __restrict__ wsb)
{
  int i = blockIdx.x*256 + threadIdx.x;
  if (i >= 32768) return;
  int m = i >> 11;
  int j = i & 2047;
  int r = j >> 4, c = j & 15;
  const float* src;
  if (m == 0)       src = lin1W;
  else if (m < 4)   src = gcnW + (m-1)*16384;
  else if (m < 7)   src = Ws   + (m-4)*16384;
  else if (m < 10)  src = Wn   + (m-7)*16384;
  else if (m < 13)  src = ginW + (m-10)*16384;
  else              src = gatW + (m-13)*16384;
  int dj = r*16 + (c ^ (r & 15));
  *(uint4*)(wsb + ((size_t)m*2048 + dj)*8) = cvt8(src + r*HD + c*8);
}

// =============== CSR build via bucketed counting sort of edges =============
// R11 post-mortem: k_fill's random 4B scatters -> 52.6MB WRITE_SIZE (16x
// amplification, line ping-pong across XCDs) = 60us; k_count has the same
// pathology on atomics. Rule: no global fine-grained scatter/atomic on random
// addresses. All fine-grained work below is LDS; all global writes are runs.

// pass 1: per-tile bucket histogram (LDS), coalesced write of eh[tile][bucket]
__global__ void k_ehist(const int* __restrict__ ei, int E, int* __restrict__ eh){
  __shared__ int h[256];
  int t = threadIdx.x, b = blockIdx.x;
  h[t] = 0; __syncthreads();
  int base = b*ETILE;
  #pragma unroll
  for (int r = 0; r < ETILE/256; r++){
    int e = base + r*256 + t;
    if (e < E) atomicAdd(&h[ei[E + e] >> 8], 1);
  }
  __syncthreads();
  eh[b*256 + t] = h[t];
}
// pass 2a: per-bucket exclusive scan over tiles (block per bucket), in place
__global__ void k_escan(int* __restrict__ eh, int nblk, int* __restrict__ btot){
  __shared__ int s[256];
  int b = blockIdx.x, t = threadIdx.x;
  int carry = 0;
  int rounds = (nblk + 255)/256;
  for (int r = 0; r < rounds; r++){
    int i = r*256 + t;
    int v = (i < nblk) ? eh[i*256 + b] : 0;
    s[t] = v; __syncthreads();
    for (int off = 1; off < 256; off <<= 1){
      int a = (t >= off) ? s[t - off] : 0;
      __syncthreads();
      s[t] += a;
      __syncthreads();
    }
    if (i < nblk) eh[i*256 + b] = s[t] - v + carry;
    carry += s[255];
    __syncthreads();
  }
  if (t == 0) btot[b] = carry;
}
// pass 2b: bucket bases (single block; B <= 256)
__global__ void k_bscan(const int* __restrict__ btot, int B, int E, int* __restrict__ bbase){
  __shared__ int s[256];
  int t = threadIdx.x;
  int v = (t < B) ? btot[t] : 0;
  s[t] = v; __syncthreads();
  for (int off = 1; off < 256; off <<= 1){
    int a = (t >= off) ? s[t - off] : 0;
    __syncthreads();
    s[t] += a;
    __syncthreads();
  }
  if (t < B) bbase[t] = s[t] - v;
  if (t == 0) bbase[B] = E;
}
// pass 3: scatter (src,dst) records bucket-grouped
__global__ void k_escat(const int* __restrict__ ei, int E, int B,
                        const int* __restrict__ eh, const int* __restrict__ bbase,
                        int2* __restrict__ ebuf){
  __shared__ int cur[256];
  int t = threadIdx.x, b = blockIdx.x;
  cur[t] = (t < B) ? bbase[t] + eh[b*256 + t] : 0;
  __syncthreads();
  int base = b*ETILE;
  #pragma unroll
  for (int r = 0; r < ETILE/256; r++){
    int e = base + r*256 + t;
    if (e < E){
      int sv = ei[e], dv = ei[E + e];
      int p = atomicAdd(&cur[dv >> 8], 1);
      ebuf[p] = make_int2(sv, dv);
    }
  }
}
// pass 4: per-bucket per-node degree count (LDS), coalesced cnt write
__global__ void k_bcount(const int2* __restrict__ ebuf, const int* __restrict__ bbase,
                         int Nn, int* __restrict__ cnt){
  __shared__ int c[256];
  int t = threadIdx.x, b = blockIdx.x;
  c[t] = 0; __syncthreads();
  int beg = bbase[b], end2 = bbase[b+1];
  for (int i = beg + t; i < end2; i += 256)
    atomicAdd(&c[ebuf[i].y & 255], 1);
  __syncthreads();
  int node = b*256 + t;
  if (node < Nn) cnt[node] = c[t];
}
// pass 5: fill csr; LDS cursors seeded from rowptr
__global__ void k_bfill(const int2* __restrict__ ebuf, const int* __restrict__ bbase,
                        const int* __restrict__ rowptr, int Nn, int* __restrict__ csr){
  __shared__ int cu[256];
  int t = threadIdx.x, b = blockIdx.x;
  int node = b*256 + t;
  cu[t] = (node < Nn) ? rowptr[node] : 0;
  __syncthreads();
  int beg = bbase[b], end2 = bbase[b+1];
  for (int i = beg + t; i < end2; i += 256){
    int2 ed = ebuf[i];
    int p = atomicAdd(&cu[ed.y & 255], 1);
    csr[p] = ed.x;
  }
}

// ---------------- rowptr scans ----------------
__global__ void k_scan1(const int* __restrict__ cnt, int Nn, int* __restrict__ bsum){
  __shared__ int red[256];
  int b = blockIdx.x, t = threadIdx.x;
  int base = b*1024 + t*4;
  int s = 0;
  #pragma unroll
  for (int k = 0; k < 4; k++){ int i = base + k; if (i < Nn) s += cnt[i]; }
  red[t] = s; __syncthreads();
  for (int off = 128; off; off >>= 1){
    if (t < off) red[t] += red[t + off];
    __syncthreads();
  }
  if (t == 0) bsum[b] = red[0];
}

__global__ void k_scan2(const int* __restrict__ bsum, int nb,
                        int* __restrict__ boffs, int* __restrict__ rowptr, int Nn){
  __shared__ int sc[1024];
  int t = threadIdx.x;
  int own = (t < nb) ? bsum[t] : 0;
  sc[t] = own;
  __syncthreads();
  for (int off = 1; off < 1024; off <<= 1){
    int add = (t >= off) ? sc[t - off] : 0;
    __syncthreads();
    sc[t] += add;
    __syncthreads();
  }
  if (t < nb) boffs[t] = sc[t] - own;
  if (t == 1023) rowptr[Nn] = sc[1023];
}

__global__ void k_scan3(const int* __restrict__ cnt, const int* __restrict__ boffs, int Nn,
                        int* __restrict__ rowptr, float4* __restrict__ nd){
  __shared__ int red[256];
  int b = blockIdx.x, t = threadIdx.x;
  int base = b*1024 + t*4;
  int c[4]; int s = 0;
  #pragma unroll
  for (int k = 0; k < 4; k++){ int i = base + k; c[k] = (i < Nn) ? cnt[i] : 0; s += c[k]; }
  red[t] = s; __syncthreads();
  for (int off = 1; off < 256; off <<= 1){
    int add = (t >= off) ? red[t - off] : 0;
    __syncthreads();
    red[t] += add;
    __syncthreads();
  }
  int run = red[t] - s + boffs[b];
  #pragma unroll
  for (int k = 0; k < 4; k++){
    int i = base + k;
    if (i < Nn){
      rowptr[i] = run;
      float f = (float)c[k];
      nd[i].z = c[k] > 0 ? 1.f/sqrtf(f) : 0.f;   // dis
      nd[i].w = 1.f/fmaxf(f, 1.f);               // dinv
      run += c[k];
    }
  }
}

// ------- degree-binned node permutation, LDS-histogram counting sort -------
// DESCENDING degree: heavy nodes dispatch first (LPT scheduling -> light tail).
__global__ void k_histblk(const int* __restrict__ cnt, int Nn, int* __restrict__ bh){
  __shared__ int h[256];
  int t = threadIdx.x, b = blockIdx.x;
  h[t] = 0; __syncthreads();
  int base = b*1024;
  #pragma unroll
  for (int k = 0; k < 4; k++){
    int i = base + t + k*256;
    if (i < Nn){ int d = cnt[i]; if (d > 255) d = 255; atomicAdd(&h[d], 1); }
  }
  __syncthreads();
  bh[b*256 + t] = h[t];
}
__global__ void k_hsscan(int* __restrict__ bh, int nb){
  __shared__ int tot[256];
  __shared__ int sc[256];
  int t = threadIdx.x;
  int s = 0;
  for (int b = 0; b < nb; b++){
    int v = bh[b*256 + t];
    bh[b*256 + t] = s;
    s += v;
  }
  tot[t] = s;
  int rt = 255 - t;            // position in DESCENDING-degree order
  __syncthreads();
  sc[rt] = tot[t];
  __syncthreads();
  for (int off = 1; off < 256; off <<= 1){
    int a = (rt >= off) ? sc[rt - off] : 0;
    __syncthreads();
    sc[rt] += a;
    __syncthreads();
  }
  int binbase = sc[rt] - tot[t];
  for (int b = 0; b < nb; b++) bh[b*256 + t] += binbase;
}
__global__ void k_permscat(const int* __restrict__ cnt, int Nn,
                           const int* __restrict__ bh, int* __restrict__ perm){
  __shared__ int cur[256];
  int t = threadIdx.x, b = blockIdx.x;
  cur[t] = bh[b*256 + t];
  __syncthreads();
  int base = b*1024;
  #pragma unroll
  for (int k = 0; k < 4; k++){
    int i = base + t + k*256;
    if (i < Nn){
      int d = cnt[i]; if (d > 255) d = 255;
      int p = atomicAdd(&cur[d], 1);
      perm[p] = i;
    }
  }
}

// ------- aggregation: ONE NODE PER 16-LANE GROUP, single pass --------------
// R10: group-per-node removed the 26-value shfl butterfly + masked epilogue.
// R11: latency-bound on csr->nd/X chain -> 4-edge software pipeline.
__global__ __launch_bounds__(256)
void k_agg(const u16* __restrict__ X, const int* __restrict__ rowptr, const int* __restrict__ csr,
           const int* __restrict__ perm,
           const float4* __restrict__ nd, const float* __restrict__ sm,
           const u32* __restrict__ maxs, int layer, int Nn,
           u16* __restrict__ Qb, u16* __restrict__ Pm, u16* __restrict__ Gb, u16* __restrict__ Rb,
           float* __restrict__ b0)
{
  int tid = threadIdx.x;
  int lane = tid & 63;
  int g = lane >> 4, t = lane & 15;
  int idx = blockIdx.x*16 + (tid >> 6)*4 + g;
  if (idx >= Nn) return;          // group-level divergence; no barriers below
  int wv = perm[idx];
  int beg = rowptr[wv], end = rowptr[wv+1];
  float4 ndw = nd[wv];
  float dval = ndw.y;
  float bnd = fdec(maxs[layer]) + dval;
  float mloc = fmaxf(bnd, 0.2f*bnd);
  f32x2 p2[4], q2[4], r2[4];
  #pragma unroll
  for (int k = 0; k < 4; k++){ p2[k] = (f32x2){0.f,0.f}; q2[k] = (f32x2){0.f,0.f}; r2[k] = (f32x2){0.f,0.f}; }
  float z = 0.f, qd = 0.f;
  int e = beg;
  // ---- 4-edge pipelined main loop ----
  int nsv0=0, nsv1=0, nsv2=0, nsv3=0;
  if (e + 3 < end){ nsv0 = csr[e]; nsv1 = csr[e+1]; nsv2 = csr[e+2]; nsv3 = csr[e+3]; }
  while (e + 3 < end){
    int sv0 = nsv0, sv1 = nsv1, sv2 = nsv2, sv3 = nsv3;
    int en = e + 4;
    if (en + 3 < end){ nsv0 = csr[en]; nsv1 = csr[en+1]; nsv2 = csr[en+2]; nsv3 = csr[en+3]; }
    float4 n0 = nd[sv0], n1 = nd[sv1], n2 = nd[sv2], n3 = nd[sv3];
    uint4 xv0 = *(const uint4*)(X + (size_t)sv0*HD + (t ^ (sv0 & 15))*8);
    uint4 xv1 = *(const uint4*)(X + (size_t)sv1*HD + (t ^ (sv1 & 15))*8);
    uint4 xv2 = *(const uint4*)(X + (size_t)sv2*HD + (t ^ (sv2 & 15))*8);
    uint4 xv3 = *(const uint4*)(X + (size_t)sv3*HD + (t ^ (sv3 & 15))*8);
    float s0 = n0.x + dval, s1 = n1.x + dval, s2 = n2.x + dval, s3 = n3.x + dval;
    float lg0 = fmaxf(s0, 0.2f*s0), lg1 = fmaxf(s1, 0.2f*s1);
    float lg2 = fmaxf(s2, 0.2f*s2), lg3 = fmaxf(s3, 0.2f*s3);
    float ew0 = __expf(lg0 - mloc), ew1 = __expf(lg1 - mloc);
    float ew2 = __expf(lg2 - mloc), ew3 = __expf(lg3 - mloc);
    u32 a0[4] = {xv0.x, xv0.y, xv0.z, xv0.w};
    u32 a1[4] = {xv1.x, xv1.y, xv1.z, xv1.w};
    u32 a2[4] = {xv2.x, xv2.y, xv2.z, xv2.w};
    u32 a3[4] = {xv3.x, xv3.y, xv3.z, xv3.w};
    f32x2 d0 = {n0.z, n0.z}, d1 = {n1.z, n1.z}, d2 = {n2.z, n2.z}, d3 = {n3.z, n3.z};
    f32x2 e0 = {ew0, ew0}, e1v = {ew1, ew1}, e2v = {ew2, ew2}, e3v = {ew3, ew3};
    #pragma unroll
    for (int k = 0; k < 4; k++){
      f32x2 xf0 = {lo2f(a0[k]), hi2f(a0[k])};
      f32x2 xf1 = {lo2f(a1[k]), hi2f(a1[k])};
      f32x2 xf2 = {lo2f(a2[k]), hi2f(a2[k])};
      f32x2 xf3 = {lo2f(a3[k]), hi2f(a3[k])};
      p2[k] += (xf0 + xf1) + (xf2 + xf3);
      q2[k] = __builtin_elementwise_fma(xf0, d0, q2[k]);
      q2[k] = __builtin_elementwise_fma(xf1, d1, q2[k]);
      q2[k] = __builtin_elementwise_fma(xf2, d2, q2[k]);
      q2[k] = __builtin_elementwise_fma(xf3, d3, q2[k]);
      r2[k] = __builtin_elementwise_fma(xf0, e0, r2[k]);
      r2[k] = __builtin_elementwise_fma(xf1, e1v, r2[k]);
      r2[k] = __builtin_elementwise_fma(xf2, e2v, r2[k]);
      r2[k] = __builtin_elementwise_fma(xf3, e3v, r2[k]);
    }
    z += (ew0 + ew1) + (ew2 + ew3);
    qd += (n0.z + n1.z) + (n2.z + n3.z);
    e = en;
  }
  // ---- 2-edge tail ----
  if (e + 1 < end){
    int sv0 = csr[e], sv1 = csr[e+1];
    float4 n0 = nd[sv0], n1 = nd[sv1];
    uint4 xv0 = *(const uint4*)(X + (size_t)sv0*HD + (t ^ (sv0 & 15))*8);
    uint4 xv1 = *(const uint4*)(X + (size_t)sv1*HD + (t ^ (sv1 & 15))*8);
    float s0 = n0.x + dval, s1 = n1.x + dval;
    float lg0 = fmaxf(s0, 0.2f*s0);
    float lg1 = fmaxf(s1, 0.2f*s1);
    float ew0 = __expf(lg0 - mloc), ew1 = __expf(lg1 - mloc);
    u32 a0[4] = {xv0.x, xv0.y, xv0.z, xv0.w};
    u32 a1[4] = {xv1.x, xv1.y, xv1.z, xv1.w};
    f32x2 d0 = {n0.z, n0.z}, d1 = {n1.z, n1.z};
    f32x2 e0 = {ew0, ew0},   e1v = {ew1, ew1};
    #pragma unroll
    for (int k = 0; k < 4; k++){
      f32x2 xf0 = {lo2f(a0[k]), hi2f(a0[k])};
      f32x2 xf1 = {lo2f(a1[k]), hi2f(a1[k])};
      p2[k] += xf0 + xf1;
      q2[k] = __builtin_elementwise_fma(xf0, d0, q2[k]);
      q2[k] = __builtin_elementwise_fma(xf1, d1, q2[k]);
      r2[k] = __builtin_elementwise_fma(xf0, e0, r2[k]);
      r2[k] = __builtin_elementwise_fma(xf1, e1v, r2[k]);
    }
    z += ew0 + ew1; qd += n0.z + n1.z;
    e += 2;
  }
  // ---- 1-edge tail ----
  if (e < end){
    int sv = csr[e];
    float4 n0 = nd[sv];
    uint4 xv = *(const uint4*)(X + (size_t)sv*HD + (t ^ (sv & 15))*8);
    float s = n0.x + dval;
    float lg = fmaxf(s, 0.2f*s);
    float ew = __expf(lg - mloc);
    u32 a0[4] = {xv.x, xv.y, xv.z, xv.w};
    f32x2 d0 = {n0.z, n0.z}, e0 = {ew, ew};
    #pragma unroll
    for (int k = 0; k < 4; k++){
      f32x2 xf = {lo2f(a0[k]), hi2f(a0[k])};
      p2[k] += xf;
      q2[k] = __builtin_elementwise_fma(xf, d0, q2[k]);
      r2[k] = __builtin_elementwise_fma(xf, e0, r2[k]);
    }
    z += ew; qd += n0.z;
  }
  // epilogue: all 16 lanes of the group store their own chunk (4 nodes/wave)
  {
    float disv = ndw.z, dinvv = ndw.w;
    float zinv = 1.f/(z + 1e-16f);
    float e1 = sm[17 + layer];
    int tch = t ^ (wv & 15);
    size_t o = (size_t)wv*HD + tch*8;
    uint4 xo = *(const uint4*)(X + o);
    u32 ax[4] = {xo.x, xo.y, xo.z, xo.w};
    uint4 qo, po, go, ro;
    u32* qp = (u32*)&qo; u32* pp = (u32*)&po; u32* gp = (u32*)&go; u32* rp = (u32*)&ro;
    #pragma unroll
    for (int k = 0; k < 4; k++){
      float x0 = lo2f(ax[k]), x1 = hi2f(ax[k]);
      qp[k] = pack2(disv*q2[k].x, disv*q2[k].y);
      pp[k] = pack2(dinvv*p2[k].x, dinvv*p2[k].y);
      gp[k] = pack2(fmaf(e1, x0, p2[k].x), fmaf(e1, x1, p2[k].y));
      rp[k] = pack2(zinv*r2[k].x, zinv*r2[k].y);
    }
    *(uint4*)(Qb + o) = qo;
    *(uint4*)(Pm + o) = po;
    *(uint4*)(Gb + o) = go;
    *(uint4*)(Rb + o) = ro;
    if (t == 0) b0[wv] = disv*qd;
  }
}

// ---------------- MFMA helpers, M=64 tile (LDS path: k_gemm1 only) ---------
__device__ __forceinline__ void stageB_async(u16* lds, const u16* __restrict__ w, int tid){
  int lane = tid & 63, wave = tid >> 6;
  #pragma unroll
  for (int i = 0; i < 8; i++){
    int cb = wave*64 + 256*i;
    async16(w + (size_t)(cb + lane)*8, lds + (size_t)cb*8);
  }
}
__device__ __forceinline__ void stageA64_f32(u16* lds, const float* __restrict__ src,
                                             int mbase, int Nn, int tid){
  #pragma unroll
  for (int i = 0; i < 4; i++){
    int chunk = tid + 256*i;
    int r = chunk >> 4;
    int c = chunk & 15;
    uint4 v = {0u,0u,0u,0u};
    int gr = mbase + r;
    if (gr < Nn) v = cvt8(src + (size_t)gr*HD + c*8);
    *(uint4*)(lds + (r*16 + (c ^ (r & 15)))*8) = v;
  }
}
__device__ __forceinline__ void mfma_tile64(const u16* Als, const u16* Bls,
                                            int m0, int lane, f32x4 acc[8]){
  int quad = lane >> 4, lr = lane & 15;
  #pragma unroll
  for (int ks = 0; ks < 4; ks++){
    int q = ks*4 + quad;
    short8 a, b[8];
    int row = m0 + lr;
    a = *(const short8*)(Als + (row*16 + (q ^ lr))*8);
    #pragma unroll
    for (int ct = 0; ct < 8; ct++){
      int brow = ct*16 + lr;
      b[ct] = *(const short8*)(Bls + (brow*16 + (q ^ lr))*8);
    }
    #pragma unroll
    for (int ct = 0; ct < 8; ct++)
      acc[ct] = __builtin_amdgcn_mfma_f32_16x16x32_bf16(a, b[ct], acc[ct], 0, 0, 0);
  }
}

// ---------------- lin1: xh(bf16,swz) = f32(x) @ W^T + b ----------------
__global__ __launch_bounds__(256,3)
void k_gemm1(const float* __restrict__ A, const u16* __restrict__ Wb, const float* __restrict__ bias,
             const float* __restrict__ sm, float4* __restrict__ nd, u32* __restrict__ maxs,
             int Nn, u16* __restrict__ out)
{
  __shared__ __align__(16) u16 Als[64*128];
  __shared__ __align__(16) u16 Bls[128*128];
  __shared__ float mred[4];
  int tid = threadIdx.x;
  int lane = tid & 63, wave = tid >> 6;
  int m0 = wave*16, mbase = blockIdx.x*64;
  int quad = lane >> 4, lr = lane & 15;
  f32x4 acc[8];
  #pragma unroll
  for (int ct=0;ct<8;ct++) acc[ct] = (f32x4){0.f,0.f,0.f,0.f};
  stageB_async(Bls, Wb, tid);
  stageA64_f32(Als, A, mbase, Nn, tid);
  __syncthreads();
  mfma_tile64(Als, Bls, m0, lane, acc);
  #pragma unroll
  for (int ct=0;ct<8;ct++){
    float bc = bias[ct*16+lr];
    #pragma unroll
    for (int r=0;r<4;r++) acc[ct][r] = sane(acc[ct][r] + bc);
  }
  #pragma unroll
  for (int ct=0;ct<8;ct++){
    int c2 = ct*2 + (lr >> 3);
    #pragma unroll
    for (int r=0;r<4;r++){
      int grow = mbase + m0 + quad*4 + r;
      if (grow < Nn) out[(size_t)grow*HD + (c2 ^ (grow & 15))*8 + (lr & 7)] = f2b(acc[ct][r]);
    }
  }
  {
    const float* wsv = sm + 32;
    const float* wdv = sm + 416;
    float sp[4] = {0.f,0.f,0.f,0.f}, dp[4] = {0.f,0.f,0.f,0.f};
    #pragma unroll
    for (int ct=0;ct<8;ct++){
      float wsc = wsv[ct*16+lr], wdc = wdv[ct*16+lr];
      #pragma unroll
      for (int r=0;r<4;r++){
        sp[r] = fmaf(acc[ct][r], wsc, sp[r]);
        dp[r] = fmaf(acc[ct][r], wdc, dp[r]);
      }
    }
    #pragma unroll
    for (int off=1; off<16; off<<=1)
      #pragma unroll
      for (int r=0;r<4;r++){ sp[r] += __shfl_xor(sp[r], off); dp[r] += __shfl_xor(dp[r], off); }
    float ms = -3.4e38f;
    #pragma unroll
    for (int r=0;r<4;r++){
      int grow = mbase + m0 + quad*4 + r;
      if (grow < Nn){
        ms = fmaxf(ms, sp[r]);
        if (lr == 0) *(float2*)&nd[grow] = make_float2(sp[r], dp[r]);
      }
    }
    ms = fmaxf(ms, __shfl_xor(ms, 16));
    ms = fmaxf(ms, __shfl_xor(ms, 32));
    if (lane == 0) mred[wave] = ms;
    __syncthreads();
    if (tid == 0){
      float m = fmaxf(fmaxf(mred[0],mred[1]), fmaxf(mred[2],mred[3]));
      atomicMax(maxs + 0, fenc(m));
    }
  }
}

// ------- fused layer: BARRIER-FREE all-register GEMMs (R12 rewrite) --------
// R12 rationale: previous version had MfmaUtil 5.8 / VALU 16 / HBM 24 /
// Occ 18 — nothing busy: the 5x {async-stage -> syncthreads(vmcnt 0 drain) ->
// mfma -> syncthreads} structure serialized on staging latency with only
// ~3 blocks/CU resident. All A inputs and B weights are ALREADY stored in
// the MFMA fragment layout (staging copy was linear), so each lane loads its
// short8 fragments DIRECTLY global->VGPR: no LDS, no barriers in the GEMM
// body. Latency hidden by scoreboard + 12 waves/CU + one-op-ahead A prefetch
// (2-deep register rotation, statically indexed — rule #20).
__global__ __launch_bounds__(256,3)
void k_layer3(const u16* __restrict__ X, const u16* __restrict__ Qb,
              const u16* __restrict__ Pm, const u16* __restrict__ Gb, const u16* __restrict__ Rb,
              float4* __restrict__ nd, const float* __restrict__ b0,
              const u16* __restrict__ wsb,
              const float* __restrict__ gcnB, const float* __restrict__ ginB,
              const float* __restrict__ sm, u32* __restrict__ maxs,
              int layer, int Nn, u16* __restrict__ out)
{
  __shared__ float mred[4];
  int tid = threadIdx.x;
  int lane = tid & 63, wave = tid >> 6;
  int m0 = wave*16, mbase = blockIdx.x*64;
  int quad = lane >> 4, lr = lane & 15;
  float w0 = sm[layer*4+0], w1 = sm[layer*4+1], w2 = sm[layer*4+2], w3 = sm[layer*4+3];
  const u16* gcnWb = wsb + (size_t)(1  + layer)*16384;
  const u16* WsWb  = wsb + (size_t)(4  + layer)*16384;
  const u16* WnWb  = wsb + (size_t)(7  + layer)*16384;
  const u16* ginWb = wsb + (size_t)(10 + layer)*16384;
  const u16* gatWb = wsb + (size_t)(13 + layer)*16384;

  // A-fragment addressing: this lane always reads row (mbase+m0+lr), chunk
  // ((ks*4+quad)^lr) — exactly the producer's swizzled layout.
  int arow = mbase + m0 + lr; if (arow >= Nn) arow = Nn - 1;
  size_t abase = (size_t)arow * HD;
  int co[4];
  #pragma unroll
  for (int ks = 0; ks < 4; ks++) co[ks] = ((ks*4 + quad) ^ lr) * 8;
  int bro = lr * 128;   // B row offset in u16 (brow=ct*16+lr -> ct*2048+lr*128)

  f32x4 mix[8];
  f32x4 acc[8];
  float b0r[4];
  #pragma unroll
  for (int r=0;r<4;r++){
    int grow = mbase + m0 + quad*4 + r;
    b0r[r] = (grow < Nn) ? b0[grow] : 0.f;
  }

  short8 a0[4], a1[4];
  #pragma unroll
  for (int ks=0;ks<4;ks++) a0[ks] = *(const short8*)(Qb + abase + co[ks]);
  #pragma unroll
  for (int ks=0;ks<4;ks++) a1[ks] = *(const short8*)(X + abase + co[ks]);

  // ---- op0: GCN (A=Qb in a0) ----
  #pragma unroll
  for (int ct=0;ct<8;ct++) acc[ct] = (f32x4){0.f,0.f,0.f,0.f};
  #pragma unroll
  for (int ks=0;ks<4;ks++){
    #pragma unroll
    for (int ct=0;ct<8;ct++){
      short8 b = *(const short8*)(gcnWb + ct*2048 + bro + co[ks]);
      acc[ct] = __builtin_amdgcn_mfma_f32_16x16x32_bf16(a0[ks], b, acc[ct], 0, 0, 0);
    }
  }
  #pragma unroll
  for (int ks=0;ks<4;ks++) a0[ks] = *(const short8*)(Pm + abase + co[ks]);  // prefetch Pm
  {
    float gb[8];
    #pragma unroll
    for (int ct=0;ct<8;ct++) gb[ct] = gcnB[layer*HD + ct*16+lr];
    #pragma unroll
    for (int ct=0;ct<8;ct++)
      #pragma unroll
      for (int r=0;r<4;r++)
        mix[ct][r] = w0 * eluf(acc[ct][r] + b0r[r]*gb[ct]);
  }

  // ---- op1: SAGE self (A=X in a1) ----
  #pragma unroll
  for (int ct=0;ct<8;ct++) acc[ct] = (f32x4){0.f,0.f,0.f,0.f};
  #pragma unroll
  for (int ks=0;ks<4;ks++){
    #pragma unroll
    for (int ct=0;ct<8;ct++){
      short8 b = *(const short8*)(WsWb + ct*2048 + bro + co[ks]);
      acc[ct] = __builtin_amdgcn_mfma_f32_16x16x32_bf16(a1[ks], b, acc[ct], 0, 0, 0);
    }
  }
  #pragma unroll
  for (int ks=0;ks<4;ks++) a1[ks] = *(const short8*)(Gb + abase + co[ks]);  // prefetch Gb
  // ---- op2: SAGE neighbor (A=Pm in a0), accumulate into same acc ----
  #pragma unroll
  for (int ks=0;ks<4;ks++){
    #pragma unroll
    for (int ct=0;ct<8;ct++){
      short8 b = *(const short8*)(WnWb + ct*2048 + bro + co[ks]);
      acc[ct] = __builtin_amdgcn_mfma_f32_16x16x32_bf16(a0[ks], b, acc[ct], 0, 0, 0);
    }
  }
  #pragma unroll
  for (int ks=0;ks<4;ks++) a0[ks] = *(const short8*)(Rb + abase + co[ks]);  // prefetch Rb
  #pragma unroll
  for (int ct=0;ct<8;ct++)
    #pragma unroll
    for (int r=0;r<4;r++)
      mix[ct][r] += w1 * eluf(acc[ct][r]);

  // ---- op3: GIN (A=Gb in a1) ----
  #pragma unroll
  for (int ct=0;ct<8;ct++) acc[ct] = (f32x4){0.f,0.f,0.f,0.f};
  #pragma unroll
  for (int ks=0;ks<4;ks++){
    #pragma unroll
    for (int ct=0;ct<8;ct++){
      short8 b = *(const short8*)(ginWb + ct*2048 + bro + co[ks]);
      acc[ct] = __builtin_amdgcn_mfma_f32_16x16x32_bf16(a1[ks], b, acc[ct], 0, 0, 0);
    }
  }
  {
    float gib[8];
    #pragma unroll
    for (int ct=0;ct<8;ct++) gib[ct] = ginB[layer*HD + ct*16+lr];
    #pragma unroll
    for (int ct=0;ct<8;ct++)
      #pragma unroll
      for (int r=0;r<4;r++)
        mix[ct][r] += w2 * eluf(acc[ct][r] + gib[ct]);
  }

  // ---- op4: GAT (A=Rb in a0) ----
  #pragma unroll
  for (int ct=0;ct<8;ct++) acc[ct] = (f32x4){0.f,0.f,0.f,0.f};
  #pragma unroll
  for (int ks=0;ks<4;ks++){
    #pragma unroll
    for (int ct=0;ct<8;ct++){
      short8 b = *(const short8*)(gatWb + ct*2048 + bro + co[ks]);
      acc[ct] = __builtin_amdgcn_mfma_f32_16x16x32_bf16(a0[ks], b, acc[ct], 0, 0, 0);
    }
  }
  #pragma unroll
  for (int ct=0;ct<8;ct++)
    #pragma unroll
    for (int r=0;r<4;r++)
      mix[ct][r] = sane(mix[ct][r] + w3 * eluf(acc[ct][r]));

  // ---- store swizzled ----
  #pragma unroll
  for (int ct=0;ct<8;ct++){
    int c2 = ct*2 + (lr >> 3);
    #pragma unroll
    for (int r=0;r<4;r++){
      int grow = mbase + m0 + quad*4 + r;
      if (grow < Nn) out[(size_t)grow*HD + (c2 ^ (grow & 15))*8 + (lr & 7)] = f2b(mix[ct][r]);
    }
  }
  // ---- epilogue: s,d for next layer + global maxS ----
  if (layer < 2){
    const float* wsv = sm + 32  + (layer+1)*128;
    const float* wdv = sm + 416 + (layer+1)*128;
    float sp[4] = {0.f,0.f,0.f,0.f}, dp[4] = {0.f,0.f,0.f,0.f};
    #pragma unroll
    for (int ct=0;ct<8;ct++){
      float wsc = wsv[ct*16+lr], wdc = wdv[ct*16+lr];
      #pragma unroll
      for (int r=0;r<4;r++){
        sp[r] = fmaf(mix[ct][r], wsc, sp[r]);
        dp[r] = fmaf(mix[ct][r], wdc, dp[r]);
      }
    }
    #pragma unroll
    for (int off=1; off<16; off<<=1)
      #pragma unroll
      for (int r=0;r<4;r++){ sp[r] += __shfl_xor(sp[r], off); dp[r] += __shfl_xor(dp[r], off); }
    float ms = -3.4e38f;
    #pragma unroll
    for (int r=0;r<4;r++){
      int grow = mbase + m0 + quad*4 + r;
      if (grow < Nn){
        ms = fmaxf(ms, sp[r]);
        if (lr == 0) *(float2*)&nd[grow] = make_float2(sp[r], dp[r]);
      }
    }
    ms = fmaxf(ms, __shfl_xor(ms, 16));
    ms = fmaxf(ms, __shfl_xor(ms, 32));
    if (lane == 0) mred[wave] = ms;
    __syncthreads();
    if (tid == 0){
      float m = fmaxf(fmaxf(mred[0],mred[1]), fmaxf(mred[2],mred[3]));
      atomicMax(maxs + layer + 1, fenc(m));
    }
  }
}

// ------- classifier with fused skip/layer-agg (inputs swizzled) ----------
__global__ __launch_bounds__(256)
void k_nc(const u16* __restrict__ X1, const u16* __restrict__ X2, const u16* __restrict__ X3,
          const float* __restrict__ W, const float* __restrict__ bias,
          const float* __restrict__ sm, int Nn, float* __restrict__ out)
{
  __shared__ __align__(16) u16 xs[32*136];
  __shared__ __align__(16) float wn[40*132];
  __shared__ float bs[40];
  int t = threadIdx.x;
  int nb = blockIdx.x*32;
  float c1 = sm[12], c2 = sm[13], la0 = sm[14], la1 = sm[15], la2 = sm[16];
  #pragma unroll
  for (int i = 0; i < 2; i++){
    int chunk = t + 256*i;
    int r = chunk >> 4, c = chunk & 15;
    uint4 v = {0u,0u,0u,0u};
    int gr = nb + r;
    if (gr < Nn){
      size_t o = (size_t)gr*HD + ((c ^ (gr & 15))*8);
      uint4 u1 = *(const uint4*)(X1 + o);
      uint4 u2 = *(const uint4*)(X2 + o);
      uint4 u3 = *(const uint4*)(X3 + o);
      u32* u1p = (u32*)&u1; u32* u2p = (u32*)&u2; u32* u3p = (u32*)&u3; u32* vp = (u32*)&v;
      #pragma unroll
      for (int k = 0; k < 4; k++){
        float o0, o1;
        {
          float a1 = lo2f(u1p[k]), a2 = lo2f(u2p[k]), a3 = lo2f(u3p[k]);
          float t0 = a3, t1 = c1*a1, t2 = c2*a2;
          float smm = t0 + t1 + t2;
          float mx = fmaxf(fmaxf(t0,t1),t2);
          o0 = la0*reluf(mx) + la1*reluf(smm*(1.f/3.f)) + la2*reluf(smm);
        }
        {
          float a1 = hi2f(u1p[k]), a2 = hi2f(u2p[k]), a3 = hi2f(u3p[k]);
          float t0 = a3, t1 = c1*a1, t2 = c2*a2;
          float smm = t0 + t1 + t2;
          float mx = fmaxf(fmaxf(t0,t1),t2);
          o1 = la0*reluf(mx) + la1*reluf(smm*(1.f/3.f)) + la2*reluf(smm);
        }
        vp[k] = pack2(sane(o0), sane(o1));
      }
    }
    *(uint4*)(xs + r*136 + c*8) = v;
  }
  #pragma unroll
  for (int i = 0; i < 5; i++){
    int chunk = t + 256*i;
    int r = chunk >> 5, c = chunk & 31;
    *(float4*)(wn + r*132 + c*4) = *(const float4*)(W + r*HD + c*4);
  }
  if (t < 40) bs[t] = bias[t];
  __syncthreads();
  int nl = t >> 3, cg = t & 7;
  float acc[5];
  #pragma unroll
  for (int j = 0; j < 5; j++) acc[j] = bs[cg + 8*j];
  for (int k = 0; k < 128; k++){
    float xv = b2f(xs[nl*136 + k]);
    #pragma unroll
    for (int j = 0; j < 5; j++)
      acc[j] = fmaf(xv, wn[(cg + 8*j)*132 + k], acc[j]);
  }
  int gr = nb + nl;
  if (gr < Nn){
    #pragma unroll
    for (int j = 0; j < 5; j++)
      out[(size_t)gr*40 + cg + 8*j] = sane(acc[j]);
  }
}

// ---------------- host ----------------
extern "C" void kernel_launch(void* const* d_in, const int* in_sizes, int n_in,
                              void* d_out, int out_size, void* d_ws, size_t ws_size,
                              hipStream_t stream)
{
  (void)n_in; (void)out_size; (void)ws_size;
  const int N = in_sizes[0] / HD;
  const int E = in_sizes[1] / 2;
  const float* x      = (const float*)d_in[0];
  const int*   ei     = (const int*)d_in[1];
  const float* na_a   = (const float*)d_in[2];
  const float* sc_a   = (const float*)d_in[3];
  const float* la_a   = (const float*)d_in[4];
  const float* lin1W  = (const float*)d_in[5];
  const float* lin1b  = (const float*)d_in[6];
  const float* gcnW   = (const float*)d_in[7];
  const float* gcnB   = (const float*)d_in[8];
  const float* sageWs = (const float*)d_in[9];
  const float* sageWn = (const float*)d_in[10];
  const float* ginW   = (const float*)d_in[11];
  const float* ginB   = (const float*)d_in[12];
  const float* ginE   = (const float*)d_in[13];
  const float* gatW   = (const float*)d_in[14];
  const float* gatAs  = (const float*)d_in[15];
  const float* gatAd  = (const float*)d_in[16];
  const float* ncW    = (const float*)d_in[17];
  const float* ncB    = (const float*)d_in[18];

  char* base = (char*)d_ws;
  size_t off = 0;
  auto alloc = [&](size_t b) -> void* {
    void* p = base + off;
    off += (b + 255) & ~(size_t)255;
    return p;
  };
  const int NB  = (N + 1023) / 1024;       // 1024-node scan blocks
  const int B   = (N + 255) >> 8;          // 256-node edge buckets (<=256)
  const int nbe = (E + ETILE - 1) / ETILE; // edge tiles
  float*  smalls = (float*)alloc(4096);
  u32*    maxs   = (u32*)alloc(256);
  int*    cnt    = (int*)alloc((size_t)N*4);
  int*    rowptr = (int*)alloc(((size_t)N+1)*4);
  int*    bsum   = (int*)alloc(4096);
  int*    boffs  = (int*)alloc(4096);
  int*    bh     = (int*)alloc((size_t)NB*256*4);
  int*    perm   = (int*)alloc((size_t)N*4);
  int*    eh     = (int*)alloc((size_t)nbe*256*4);
  int*    btot   = (int*)alloc(1024);
  int*    bbase  = (int*)alloc(1040);
  float4* nd     = (float4*)alloc((size_t)N*16);
  float*  b0     = (float*)alloc((size_t)N*4);
  int*    csr    = (int*)alloc((size_t)E*4);
  u16*    wsb    = (u16*)alloc((size_t)16*16384*2);
  u16*    xh     = (u16*)alloc((size_t)N*HD*2);
  u16*    x1     = (u16*)alloc((size_t)N*HD*2);
  u16*    x2     = (u16*)alloc((size_t)N*HD*2);
  u16*    Qb     = (u16*)alloc((size_t)N*HD*2);
  u16*    Pm     = (u16*)alloc((size_t)N*HD*2);
  u16*    Gb     = (u16*)alloc((size_t)N*HD*2);
  u16*    Rb     = (u16*)alloc((size_t)N*HD*2);
  // ebuf (E*8 = 6.4MB) aliases Qb (12.8MB): k_bfill completes before k_agg
  // first writes Qb (stream-ordered), so no overlap in lifetime.
  int2*   ebuf   = (int2*)Qb;

  k_small<<<1,128,0,stream>>>(na_a, sc_a, la_a, gatW, gatAs, gatAd, ginE, smalls, maxs);
  k_wcvt<<<128,256,0,stream>>>(lin1W, gcnW, sageWs, sageWn, ginW, gatW, wsb);
  // ---- CSR build: bucketed counting sort, zero global fine-grained atomics
  k_ehist<<<nbe,256,0,stream>>>(ei, E, eh);
  k_escan<<<B,256,0,stream>>>(eh, nbe, btot);
  k_bscan<<<1,256,0,stream>>>(btot, B, E, bbase);
  k_escat<<<nbe,256,0,stream>>>(ei, E, B, eh, bbase, ebuf);
  k_bcount<<<B,256,0,stream>>>(ebuf, bbase, N, cnt);
  k_histblk<<<NB,256,0,stream>>>(cnt, N, bh);
  k_hsscan<<<1,256,0,stream>>>(bh, NB);
  k_permscat<<<NB,256,0,stream>>>(cnt, N, bh, perm);
  k_scan1<<<NB,256,0,stream>>>(cnt, N, bsum);
  k_scan2<<<1,1024,0,stream>>>(bsum, NB, boffs, rowptr, N);
  k_scan3<<<NB,256,0,stream>>>(cnt, boffs, N, rowptr, nd);
  k_bfill<<<B,256,0,stream>>>(ebuf, bbase, rowptr, N, csr);
  int gbl64 = (N + 63)/64;
  k_gemm1<<<gbl64,256,0,stream>>>(x, wsb, lin1b, smalls, nd, maxs, N, xh);
  const u16* xc = xh;
  u16* outs[3] = {x1, x2, xh};
  int abl = (N + 15)/16;
  for (int l = 0; l < 3; l++){
    k_agg<<<abl,256,0,stream>>>(xc, rowptr, csr, perm, nd, smalls, maxs, l, N, Qb, Pm, Gb, Rb, b0);
    k_layer3<<<gbl64,256,0,stream>>>(xc, Qb, Pm, Gb, Rb, nd, b0, wsb,
                                     gcnB, ginB, smalls, maxs, l, N, outs[l]);
    xc = outs[l];
  }
  int ncbl = (N + 31)/32;
  k_nc<<<ncbl,256,0,stream>>>(x1, x2, xh, ncW, ncB, smalls, N, (float*)d_out);
}

// Round 5
// 438.471 us; speedup vs baseline: 1.1679x; 1.1679x over previous
//
#include <hip/hip_runtime.h>
#include <hip/hip_bf16.h>

typedef unsigned short u16;
typedef unsigned int u32;
typedef __attribute__((ext_vector_type(8))) short short8;
typedef __attribute__((ext_vector_type(4))) float f32x4;
typedef __attribute__((ext_vector_type(2))) float f32x2;

#define HD 128
#define ETILE 8192

__device__ inline float b2f(u16 u){ u32 v = ((u32)u) << 16; return __uint_as_float(v); }
__device__ inline u16 f2b(float f){
  u32 u = __float_as_uint(f);
  u32 r = (u + 0x7fffu + ((u >> 16) & 1u)) >> 16;
  return (u16)r;
}
// packed f32x2 -> bf16x2 via HW convert
__device__ inline u32 pack2(float a, float b){
  __hip_bfloat162 h = __float22bfloat162_rn(make_float2(a, b));
  union { __hip_bfloat162 h; u32 u; } c; c.h = h; return c.u;
}
__device__ inline float lo2f(u32 w){ return b2f((u16)(w & 0xffff)); }
__device__ inline float hi2f(u32 w){ return b2f((u16)(w >> 16)); }
__device__ inline float eluf(float x){ return x > 0.f ? x : __expf(x) - 1.f; }
__device__ inline float reluf(float x){ return x > 0.f ? x : 0.f; }
__device__ inline float sane(float x){
  if (!(x == x)) return 0.f;
  return fminf(fmaxf(x, -1e30f), 1e30f);
}
// monotone float<->u32 encoding for atomicMax on signed floats
__device__ inline u32 fenc(float f){ u32 u = __float_as_uint(f); return (u & 0x80000000u) ? ~u : (u | 0x80000000u); }
__device__ inline float fdec(u32 u){ return __uint_as_float((u & 0x80000000u) ? (u & 0x7fffffffu) : ~u); }
// async 16B global->LDS
__device__ __forceinline__ void async16(const u16* g, u16* l){
  __builtin_amdgcn_global_load_lds((const __attribute__((address_space(1))) void*)g,
                                   (__attribute__((address_space(3))) void*)l, 16, 0, 0);
}

// ---------------- small precompute ----------------
__global__ void k_small(const float* __restrict__ na_a, const float* __restrict__ sc_a,
                        const float* __restrict__ la_a, const float* __restrict__ gatW,
                        const float* __restrict__ gat_as, const float* __restrict__ gat_ad,
                        const float* __restrict__ gin_eps, float* __restrict__ sm,
                        u32* __restrict__ maxs)
{
  int t = threadIdx.x;
  if (t < 3) maxs[t] = 0u;
  if (t == 0){
    for (int l = 0; l < 3; l++){
      float a[4]; float mx = -1e30f;
      for (int i = 0; i < 4; i++){ a[i] = na_a[l*4+i]; mx = fmaxf(mx, a[i]); }
      float ssum = 0.f;
      for (int i = 0; i < 4; i++){ a[i] = __expf(a[i]-mx); ssum += a[i]; }
      for (int i = 0; i < 4; i++) sm[l*4+i] = a[i]/ssum;
    }
    for (int r = 0; r < 2; r++){
      float a0 = sc_a[r*2], a1 = sc_a[r*2+1];
      float mx = fmaxf(a0,a1);
      float e0 = __expf(a0-mx), e1 = __expf(a1-mx);
      sm[12+r] = e1/(e0+e1);
    }
    {
      float a0=la_a[0], a1=la_a[1], a2=la_a[2];
      float mx = fmaxf(fmaxf(a0,a1),a2);
      float e0=__expf(a0-mx), e1=__expf(a1-mx), e2=__expf(a2-mx);
      float ssum = e0+e1+e2;
      sm[14]=e0/ssum; sm[15]=e1/ssum; sm[16]=e2/ssum;
    }
    for (int l=0;l<3;l++) sm[17+l] = 1.f + gin_eps[l];
  }
  if (t < 128){
    for (int l=0;l<3;l++){
      float a1=0.f, a2=0.f;
      for (int k=0;k<128;k++){
        float wv = gatW[l*16384 + k*128 + t];
        a1 = fmaf(wv, gat_as[l*128+k], a1);
        a2 = fmaf(wv, gat_ad[l*128+k], a2);
      }
      sm[32  + l*128 + t] = a1;
      sm[416 + l*128 + t] = a2;
    }
  }
}

// -------- weight pre-conversion f32 -> bf16, PRE-SWIZZLED chunk order -------
__device__ __forceinline__ uint4 cvt8(const float* __restrict__ p){
  float4 v0 = *(const float4*)p;
  float4 v1 = *(const float4*)(p + 4);
  uint4 o;
  o.x = pack2(v0.x, v0.y);
  o.y = pack2(v0.z, v0.w);
  o.z = pack2(v1.x, v1.y);
  o.w = pack2(v1.z, v1.w);
  return o;
}
__global__ void k_wcvt(const float* __restrict__ lin1W, const float* __restrict__ gcnW,
                       const float* __restrict__ Ws, const float* __restrict__ Wn,
                       const float* __restrict__ ginW, const float* __restrict__ gatW,
                       u16* __restrict__ wsb)
{
  int i = blockIdx.x*256 + threadIdx.x;
  if (i >= 32768) return;
  int m = i >> 11;
  int j = i & 2047;
  int r = j >> 4, c = j & 15;
  const float* src;
  if (m == 0)       src = lin1W;
  else if (m < 4)   src = gcnW + (m-1)*16384;
  else if (m < 7)   src = Ws   + (m-4)*16384;
  else if (m < 10)  src = Wn   + (m-7)*16384;
  else if (m < 13)  src = ginW + (m-10)*16384;
  else              src = gatW + (m-13)*16384;
  int dj = r*16 + (c ^ (r & 15));
  *(uint4*)(wsb + ((size_t)m*2048 + dj)*8) = cvt8(src + r*HD + c*8);
}

// =============== CSR build via bucketed counting sort of edges =============
// R11 post-mortem: k_fill's random 4B scatters -> 52.6MB WRITE_SIZE (16x
// amplification, line ping-pong across XCDs) = 60us; k_count has the same
// pathology on atomics. Rule: no global fine-grained scatter/atomic on random
// addresses. All fine-grained work below is LDS; all global writes are runs.

// pass 1: per-tile bucket histogram (LDS), coalesced write of eh[tile][bucket]
__global__ void k_ehist(const int* __restrict__ ei, int E, int* __restrict__ eh){
  __shared__ int h[256];
  int t = threadIdx.x, b = blockIdx.x;
  h[t] = 0; __syncthreads();
  int base = b*ETILE;
  #pragma unroll
  for (int r = 0; r < ETILE/256; r++){
    int e = base + r*256 + t;
    if (e < E) atomicAdd(&h[ei[E + e] >> 8], 1);
  }
  __syncthreads();
  eh[b*256 + t] = h[t];
}
// pass 2a: per-bucket exclusive scan over tiles (block per bucket), in place
__global__ void k_escan(int* __restrict__ eh, int nblk, int* __restrict__ btot){
  __shared__ int s[256];
  int b = blockIdx.x, t = threadIdx.x;
  int carry = 0;
  int rounds = (nblk + 255)/256;
  for (int r = 0; r < rounds; r++){
    int i = r*256 + t;
    int v = (i < nblk) ? eh[i*256 + b] : 0;
    s[t] = v; __syncthreads();
    for (int off = 1; off < 256; off <<= 1){
      int a = (t >= off) ? s[t - off] : 0;
      __syncthreads();
      s[t] += a;
      __syncthreads();
    }
    if (i < nblk) eh[i*256 + b] = s[t] - v + carry;
    carry += s[255];
    __syncthreads();
  }
  if (t == 0) btot[b] = carry;
}
// pass 2b: bucket bases (single block; B <= 256)
__global__ void k_bscan(const int* __restrict__ btot, int B, int E, int* __restrict__ bbase){
  __shared__ int s[256];
  int t = threadIdx.x;
  int v = (t < B) ? btot[t] : 0;
  s[t] = v; __syncthreads();
  for (int off = 1; off < 256; off <<= 1){
    int a = (t >= off) ? s[t - off] : 0;
    __syncthreads();
    s[t] += a;
    __syncthreads();
  }
  if (t < B) bbase[t] = s[t] - v;
  if (t == 0) bbase[B] = E;
}
// pass 3: scatter (src,dst) records bucket-grouped
__global__ void k_escat(const int* __restrict__ ei, int E, int B,
                        const int* __restrict__ eh, const int* __restrict__ bbase,
                        int2* __restrict__ ebuf){
  __shared__ int cur[256];
  int t = threadIdx.x, b = blockIdx.x;
  cur[t] = (t < B) ? bbase[t] + eh[b*256 + t] : 0;
  __syncthreads();
  int base = b*ETILE;
  #pragma unroll
  for (int r = 0; r < ETILE/256; r++){
    int e = base + r*256 + t;
    if (e < E){
      int sv = ei[e], dv = ei[E + e];
      int p = atomicAdd(&cur[dv >> 8], 1);
      ebuf[p] = make_int2(sv, dv);
    }
  }
}
// pass 4: per-bucket per-node degree count (LDS), coalesced cnt write
__global__ void k_bcount(const int2* __restrict__ ebuf, const int* __restrict__ bbase,
                         int Nn, int* __restrict__ cnt){
  __shared__ int c[256];
  int t = threadIdx.x, b = blockIdx.x;
  c[t] = 0; __syncthreads();
  int beg = bbase[b], end2 = bbase[b+1];
  for (int i = beg + t; i < end2; i += 256)
    atomicAdd(&c[ebuf[i].y & 255], 1);
  __syncthreads();
  int node = b*256 + t;
  if (node < Nn) cnt[node] = c[t];
}
// pass 5: fill csr; LDS cursors seeded from rowptr
__global__ void k_bfill(const int2* __restrict__ ebuf, const int* __restrict__ bbase,
                        const int* __restrict__ rowptr, int Nn, int* __restrict__ csr){
  __shared__ int cu[256];
  int t = threadIdx.x, b = blockIdx.x;
  int node = b*256 + t;
  cu[t] = (node < Nn) ? rowptr[node] : 0;
  __syncthreads();
  int beg = bbase[b], end2 = bbase[b+1];
  for (int i = beg + t; i < end2; i += 256){
    int2 ed = ebuf[i];
    int p = atomicAdd(&cu[ed.y & 255], 1);
    csr[p] = ed.x;
  }
}

// ---------------- rowptr scans ----------------
__global__ void k_scan1(const int* __restrict__ cnt, int Nn, int* __restrict__ bsum){
  __shared__ int red[256];
  int b = blockIdx.x, t = threadIdx.x;
  int base = b*1024 + t*4;
  int s = 0;
  #pragma unroll
  for (int k = 0; k < 4; k++){ int i = base + k; if (i < Nn) s += cnt[i]; }
  red[t] = s; __syncthreads();
  for (int off = 128; off; off >>= 1){
    if (t < off) red[t] += red[t + off];
    __syncthreads();
  }
  if (t == 0) bsum[b] = red[0];
}

__global__ void k_scan2(const int* __restrict__ bsum, int nb,
                        int* __restrict__ boffs, int* __restrict__ rowptr, int Nn){
  __shared__ int sc[1024];
  int t = threadIdx.x;
  int own = (t < nb) ? bsum[t] : 0;
  sc[t] = own;
  __syncthreads();
  for (int off = 1; off < 1024; off <<= 1){
    int add = (t >= off) ? sc[t - off] : 0;
    __syncthreads();
    sc[t] += add;
    __syncthreads();
  }
  if (t < nb) boffs[t] = sc[t] - own;
  if (t == 1023) rowptr[Nn] = sc[1023];
}

__global__ void k_scan3(const int* __restrict__ cnt, const int* __restrict__ boffs, int Nn,
                        int* __restrict__ rowptr, float4* __restrict__ nd){
  __shared__ int red[256];
  int b = blockIdx.x, t = threadIdx.x;
  int base = b*1024 + t*4;
  int c[4]; int s = 0;
  #pragma unroll
  for (int k = 0; k < 4; k++){ int i = base + k; c[k] = (i < Nn) ? cnt[i] : 0; s += c[k]; }
  red[t] = s; __syncthreads();
  for (int off = 1; off < 256; off <<= 1){
    int add = (t >= off) ? red[t - off] : 0;
    __syncthreads();
    red[t] += add;
    __syncthreads();
  }
  int run = red[t] - s + boffs[b];
  #pragma unroll
  for (int k = 0; k < 4; k++){
    int i = base + k;
    if (i < Nn){
      rowptr[i] = run;
      float f = (float)c[k];
      nd[i].z = c[k] > 0 ? 1.f/sqrtf(f) : 0.f;   // dis
      nd[i].w = 1.f/fmaxf(f, 1.f);               // dinv
      run += c[k];
    }
  }
}

// ------- degree-binned node permutation, LDS-histogram counting sort -------
// DESCENDING degree: heavy nodes dispatch first (LPT scheduling -> light tail).
__global__ void k_histblk(const int* __restrict__ cnt, int Nn, int* __restrict__ bh){
  __shared__ int h[256];
  int t = threadIdx.x, b = blockIdx.x;
  h[t] = 0; __syncthreads();
  int base = b*1024;
  #pragma unroll
  for (int k = 0; k < 4; k++){
    int i = base + t + k*256;
    if (i < Nn){ int d = cnt[i]; if (d > 255) d = 255; atomicAdd(&h[d], 1); }
  }
  __syncthreads();
  bh[b*256 + t] = h[t];
}
__global__ void k_hsscan(int* __restrict__ bh, int nb){
  __shared__ int tot[256];
  __shared__ int sc[256];
  int t = threadIdx.x;
  int s = 0;
  for (int b = 0; b < nb; b++){
    int v = bh[b*256 + t];
    bh[b*256 + t] = s;
    s += v;
  }
  tot[t] = s;
  int rt = 255 - t;            // position in DESCENDING-degree order
  __syncthreads();
  sc[rt] = tot[t];
  __syncthreads();
  for (int off = 1; off < 256; off <<= 1){
    int a = (rt >= off) ? sc[rt - off] : 0;
    __syncthreads();
    sc[rt] += a;
    __syncthreads();
  }
  int binbase = sc[rt] - tot[t];
  for (int b = 0; b < nb; b++) bh[b*256 + t] += binbase;
}
__global__ void k_permscat(const int* __restrict__ cnt, int Nn,
                           const int* __restrict__ bh, int* __restrict__ perm){
  __shared__ int cur[256];
  int t = threadIdx.x, b = blockIdx.x;
  cur[t] = bh[b*256 + t];
  __syncthreads();
  int base = b*1024;
  #pragma unroll
  for (int k = 0; k < 4; k++){
    int i = base + t + k*256;
    if (i < Nn){
      int d = cnt[i]; if (d > 255) d = 255;
      int p = atomicAdd(&cur[d], 1);
      perm[p] = i;
    }
  }
}

// ------- aggregation: ONE NODE PER 16-LANE GROUP, single pass --------------
// R10: group-per-node removed the 26-value shfl butterfly + masked epilogue.
// R11: latency-bound on csr->nd/X chain -> 4-edge software pipeline.
__global__ __launch_bounds__(256)
void k_agg(const u16* __restrict__ X, const int* __restrict__ rowptr, const int* __restrict__ csr,
           const int* __restrict__ perm,
           const float4* __restrict__ nd, const float* __restrict__ sm,
           const u32* __restrict__ maxs, int layer, int Nn,
           u16* __restrict__ Qb, u16* __restrict__ Pm, u16* __restrict__ Gb, u16* __restrict__ Rb,
           float* __restrict__ b0)
{
  int tid = threadIdx.x;
  int lane = tid & 63;
  int g = lane >> 4, t = lane & 15;
  int idx = blockIdx.x*16 + (tid >> 6)*4 + g;
  if (idx >= Nn) return;          // group-level divergence; no barriers below
  int wv = perm[idx];
  int beg = rowptr[wv], end = rowptr[wv+1];
  float4 ndw = nd[wv];
  float dval = ndw.y;
  float bnd = fdec(maxs[layer]) + dval;
  float mloc = fmaxf(bnd, 0.2f*bnd);
  f32x2 p2[4], q2[4], r2[4];
  #pragma unroll
  for (int k = 0; k < 4; k++){ p2[k] = (f32x2){0.f,0.f}; q2[k] = (f32x2){0.f,0.f}; r2[k] = (f32x2){0.f,0.f}; }
  float z = 0.f, qd = 0.f;
  int e = beg;
  // ---- 4-edge pipelined main loop ----
  int nsv0=0, nsv1=0, nsv2=0, nsv3=0;
  if (e + 3 < end){ nsv0 = csr[e]; nsv1 = csr[e+1]; nsv2 = csr[e+2]; nsv3 = csr[e+3]; }
  while (e + 3 < end){
    int sv0 = nsv0, sv1 = nsv1, sv2 = nsv2, sv3 = nsv3;
    int en = e + 4;
    if (en + 3 < end){ nsv0 = csr[en]; nsv1 = csr[en+1]; nsv2 = csr[en+2]; nsv3 = csr[en+3]; }
    float4 n0 = nd[sv0], n1 = nd[sv1], n2 = nd[sv2], n3 = nd[sv3];
    uint4 xv0 = *(const uint4*)(X + (size_t)sv0*HD + (t ^ (sv0 & 15))*8);
    uint4 xv1 = *(const uint4*)(X + (size_t)sv1*HD + (t ^ (sv1 & 15))*8);
    uint4 xv2 = *(const uint4*)(X + (size_t)sv2*HD + (t ^ (sv2 & 15))*8);
    uint4 xv3 = *(const uint4*)(X + (size_t)sv3*HD + (t ^ (sv3 & 15))*8);
    float s0 = n0.x + dval, s1 = n1.x + dval, s2 = n2.x + dval, s3 = n3.x + dval;
    float lg0 = fmaxf(s0, 0.2f*s0), lg1 = fmaxf(s1, 0.2f*s1);
    float lg2 = fmaxf(s2, 0.2f*s2), lg3 = fmaxf(s3, 0.2f*s3);
    float ew0 = __expf(lg0 - mloc), ew1 = __expf(lg1 - mloc);
    float ew2 = __expf(lg2 - mloc), ew3 = __expf(lg3 - mloc);
    u32 a0[4] = {xv0.x, xv0.y, xv0.z, xv0.w};
    u32 a1[4] = {xv1.x, xv1.y, xv1.z, xv1.w};
    u32 a2[4] = {xv2.x, xv2.y, xv2.z, xv2.w};
    u32 a3[4] = {xv3.x, xv3.y, xv3.z, xv3.w};
    f32x2 d0 = {n0.z, n0.z}, d1 = {n1.z, n1.z}, d2 = {n2.z, n2.z}, d3 = {n3.z, n3.z};
    f32x2 e0 = {ew0, ew0}, e1v = {ew1, ew1}, e2v = {ew2, ew2}, e3v = {ew3, ew3};
    #pragma unroll
    for (int k = 0; k < 4; k++){
      f32x2 xf0 = {lo2f(a0[k]), hi2f(a0[k])};
      f32x2 xf1 = {lo2f(a1[k]), hi2f(a1[k])};
      f32x2 xf2 = {lo2f(a2[k]), hi2f(a2[k])};
      f32x2 xf3 = {lo2f(a3[k]), hi2f(a3[k])};
      p2[k] += (xf0 + xf1) + (xf2 + xf3);
      q2[k] = __builtin_elementwise_fma(xf0, d0, q2[k]);
      q2[k] = __builtin_elementwise_fma(xf1, d1, q2[k]);
      q2[k] = __builtin_elementwise_fma(xf2, d2, q2[k]);
      q2[k] = __builtin_elementwise_fma(xf3, d3, q2[k]);
      r2[k] = __builtin_elementwise_fma(xf0, e0, r2[k]);
      r2[k] = __builtin_elementwise_fma(xf1, e1v, r2[k]);
      r2[k] = __builtin_elementwise_fma(xf2, e2v, r2[k]);
      r2[k] = __builtin_elementwise_fma(xf3, e3v, r2[k]);
    }
    z += (ew0 + ew1) + (ew2 + ew3);
    qd += (n0.z + n1.z) + (n2.z + n3.z);
    e = en;
  }
  // ---- 2-edge tail ----
  if (e + 1 < end){
    int sv0 = csr[e], sv1 = csr[e+1];
    float4 n0 = nd[sv0], n1 = nd[sv1];
    uint4 xv0 = *(const uint4*)(X + (size_t)sv0*HD + (t ^ (sv0 & 15))*8);
    uint4 xv1 = *(const uint4*)(X + (size_t)sv1*HD + (t ^ (sv1 & 15))*8);
    float s0 = n0.x + dval, s1 = n1.x + dval;
    float lg0 = fmaxf(s0, 0.2f*s0);
    float lg1 = fmaxf(s1, 0.2f*s1);
    float ew0 = __expf(lg0 - mloc), ew1 = __expf(lg1 - mloc);
    u32 a0[4] = {xv0.x, xv0.y, xv0.z, xv0.w};
    u32 a1[4] = {xv1.x, xv1.y, xv1.z, xv1.w};
    f32x2 d0 = {n0.z, n0.z}, d1 = {n1.z, n1.z};
    f32x2 e0 = {ew0, ew0},   e1v = {ew1, ew1};
    #pragma unroll
    for (int k = 0; k < 4; k++){
      f32x2 xf0 = {lo2f(a0[k]), hi2f(a0[k])};
      f32x2 xf1 = {lo2f(a1[k]), hi2f(a1[k])};
      p2[k] += xf0 + xf1;
      q2[k] = __builtin_elementwise_fma(xf0, d0, q2[k]);
      q2[k] = __builtin_elementwise_fma(xf1, d1, q2[k]);
      r2[k] = __builtin_elementwise_fma(xf0, e0, r2[k]);
      r2[k] = __builtin_elementwise_fma(xf1, e1v, r2[k]);
    }
    z += ew0 + ew1; qd += n0.z + n1.z;
    e += 2;
  }
  // ---- 1-edge tail ----
  if (e < end){
    int sv = csr[e];
    float4 n0 = nd[sv];
    uint4 xv = *(const uint4*)(X + (size_t)sv*HD + (t ^ (sv & 15))*8);
    float s = n0.x + dval;
    float lg = fmaxf(s, 0.2f*s);
    float ew = __expf(lg - mloc);
    u32 a0[4] = {xv.x, xv.y, xv.z, xv.w};
    f32x2 d0 = {n0.z, n0.z}, e0 = {ew, ew};
    #pragma unroll
    for (int k = 0; k < 4; k++){
      f32x2 xf = {lo2f(a0[k]), hi2f(a0[k])};
      p2[k] += xf;
      q2[k] = __builtin_elementwise_fma(xf, d0, q2[k]);
      r2[k] = __builtin_elementwise_fma(xf, e0, r2[k]);
    }
    z += ew; qd += n0.z;
  }
  // epilogue: all 16 lanes of the group store their own chunk (4 nodes/wave)
  {
    float disv = ndw.z, dinvv = ndw.w;
    float zinv = 1.f/(z + 1e-16f);
    float e1 = sm[17 + layer];
    int tch = t ^ (wv & 15);
    size_t o = (size_t)wv*HD + tch*8;
    uint4 xo = *(const uint4*)(X + o);
    u32 ax[4] = {xo.x, xo.y, xo.z, xo.w};
    uint4 qo, po, go, ro;
    u32* qp = (u32*)&qo; u32* pp = (u32*)&po; u32* gp = (u32*)&go; u32* rp = (u32*)&ro;
    #pragma unroll
    for (int k = 0; k < 4; k++){
      float x0 = lo2f(ax[k]), x1 = hi2f(ax[k]);
      qp[k] = pack2(disv*q2[k].x, disv*q2[k].y);
      pp[k] = pack2(dinvv*p2[k].x, dinvv*p2[k].y);
      gp[k] = pack2(fmaf(e1, x0, p2[k].x), fmaf(e1, x1, p2[k].y));
      rp[k] = pack2(zinv*r2[k].x, zinv*r2[k].y);
    }
    *(uint4*)(Qb + o) = qo;
    *(uint4*)(Pm + o) = po;
    *(uint4*)(Gb + o) = go;
    *(uint4*)(Rb + o) = ro;
    if (t == 0) b0[wv] = disv*qd;
  }
}

// ---------------- MFMA helpers, M=64 tile ----------------
__device__ __forceinline__ void stageB_async(u16* lds, const u16* __restrict__ w, int tid){
  int lane = tid & 63, wave = tid >> 6;
  #pragma unroll
  for (int i = 0; i < 8; i++){
    int cb = wave*64 + 256*i;
    async16(w + (size_t)(cb + lane)*8, lds + (size_t)cb*8);
  }
}
__device__ __forceinline__ void stageA64_f32(u16* lds, const float* __restrict__ src,
                                             int mbase, int Nn, int tid){
  #pragma unroll
  for (int i = 0; i < 4; i++){
    int chunk = tid + 256*i;
    int r = chunk >> 4;
    int c = chunk & 15;
    uint4 v = {0u,0u,0u,0u};
    int gr = mbase + r;
    if (gr < Nn) v = cvt8(src + (size_t)gr*HD + c*8);
    *(uint4*)(lds + (r*16 + (c ^ (r & 15)))*8) = v;
  }
}
__device__ __forceinline__ void mfma_tile64(const u16* Als, const u16* Bls,
                                            int m0, int lane, f32x4 acc[8]){
  int quad = lane >> 4, lr = lane & 15;
  #pragma unroll
  for (int ks = 0; ks < 4; ks++){
    int q = ks*4 + quad;
    short8 a, b[8];
    int row = m0 + lr;
    a = *(const short8*)(Als + (row*16 + (q ^ lr))*8);
    #pragma unroll
    for (int ct = 0; ct < 8; ct++){
      int brow = ct*16 + lr;
      b[ct] = *(const short8*)(Bls + (brow*16 + (q ^ lr))*8);
    }
    #pragma unroll
    for (int ct = 0; ct < 8; ct++)
      acc[ct] = __builtin_amdgcn_mfma_f32_16x16x32_bf16(a, b[ct], acc[ct], 0, 0, 0);
  }
}
// A from registers (global fragment layout), B from LDS
__device__ __forceinline__ void mfma_regA(const short8 a[4], const u16* Bls,
                                          int lane, f32x4 acc[8]){
  int quad = lane >> 4, lr = lane & 15;
  #pragma unroll
  for (int ks = 0; ks < 4; ks++){
    int q = ks*4 + quad;
    short8 b[8];
    #pragma unroll
    for (int ct = 0; ct < 8; ct++)
      b[ct] = *(const short8*)(Bls + ((ct*16 + lr)*16 + (q ^ lr))*8);
    #pragma unroll
    for (int ct = 0; ct < 8; ct++)
      acc[ct] = __builtin_amdgcn_mfma_f32_16x16x32_bf16(a[ks], b[ct], acc[ct], 0, 0, 0);
  }
}

// ---------------- lin1: xh(bf16,swz) = f32(x) @ W^T + b ----------------
__global__ __launch_bounds__(256,3)
void k_gemm1(const float* __restrict__ A, const u16* __restrict__ Wb, const float* __restrict__ bias,
             const float* __restrict__ sm, float4* __restrict__ nd, u32* __restrict__ maxs,
             int Nn, u16* __restrict__ out)
{
  __shared__ __align__(16) u16 Als[64*128];
  __shared__ __align__(16) u16 Bls[128*128];
  __shared__ float mred[4];
  int tid = threadIdx.x;
  int lane = tid & 63, wave = tid >> 6;
  int m0 = wave*16, mbase = blockIdx.x*64;
  int quad = lane >> 4, lr = lane & 15;
  f32x4 acc[8];
  #pragma unroll
  for (int ct=0;ct<8;ct++) acc[ct] = (f32x4){0.f,0.f,0.f,0.f};
  stageB_async(Bls, Wb, tid);
  stageA64_f32(Als, A, mbase, Nn, tid);
  __syncthreads();
  mfma_tile64(Als, Bls, m0, lane, acc);
  #pragma unroll
  for (int ct=0;ct<8;ct++){
    float bc = bias[ct*16+lr];
    #pragma unroll
    for (int r=0;r<4;r++) acc[ct][r] = sane(acc[ct][r] + bc);
  }
  #pragma unroll
  for (int ct=0;ct<8;ct++){
    int c2 = ct*2 + (lr >> 3);
    #pragma unroll
    for (int r=0;r<4;r++){
      int grow = mbase + m0 + quad*4 + r;
      if (grow < Nn) out[(size_t)grow*HD + (c2 ^ (grow & 15))*8 + (lr & 7)] = f2b(acc[ct][r]);
    }
  }
  {
    const float* wsv = sm + 32;
    const float* wdv = sm + 416;
    float sp[4] = {0.f,0.f,0.f,0.f}, dp[4] = {0.f,0.f,0.f,0.f};
    #pragma unroll
    for (int ct=0;ct<8;ct++){
      float wsc = wsv[ct*16+lr], wdc = wdv[ct*16+lr];
      #pragma unroll
      for (int r=0;r<4;r++){
        sp[r] = fmaf(acc[ct][r], wsc, sp[r]);
        dp[r] = fmaf(acc[ct][r], wdc, dp[r]);
      }
    }
    #pragma unroll
    for (int off=1; off<16; off<<=1)
      #pragma unroll
      for (int r=0;r<4;r++){ sp[r] += __shfl_xor(sp[r], off); dp[r] += __shfl_xor(dp[r], off); }
    float ms = -3.4e38f;
    #pragma unroll
    for (int r=0;r<4;r++){
      int grow = mbase + m0 + quad*4 + r;
      if (grow < Nn){
        ms = fmaxf(ms, sp[r]);
        if (lr == 0) *(float2*)&nd[grow] = make_float2(sp[r], dp[r]);
      }
    }
    ms = fmaxf(ms, __shfl_xor(ms, 16));
    ms = fmaxf(ms, __shfl_xor(ms, 32));
    if (lane == 0) mred[wave] = ms;
    __syncthreads();
    if (tid == 0){
      float m = fmaxf(fmaxf(mred[0],mred[1]), fmaxf(mred[2],mred[3]));
      atomicMax(maxs + 0, fenc(m));
    }
  }
}

// ------- fused layer (R14): B double-buffered in LDS staged ONE OP AHEAD,
// A direct global->reg with one-op-ahead prefetch.
// R13 post-mortem: all-register B regressed (51->60us) — B re-read per wave
// from L2 with scattered 16B loads, each MFMA serially dependent on its B
// load. LDS is the B bandwidth amplifier (staged once/block, read 4x from
// LDS). R12 post-mortem: single-buffer LDS serialized on the barrier's
// vmcnt(0) drain. Fix: stage B(k+1) BEFORE compute of op k, so the drain at
// the barrier after op k is hidden under MFMA + mix math. Only the prologue
// stage is exposed. LDS 2x32KB -> 2 blocks/CU.
__global__ __launch_bounds__(256,2)
void k_layer3(const u16* __restrict__ X, const u16* __restrict__ Qb,
              const u16* __restrict__ Pm, const u16* __restrict__ Gb, const u16* __restrict__ Rb,
              float4* __restrict__ nd, const float* __restrict__ b0,
              const u16* __restrict__ wsb,
              const float* __restrict__ gcnB, const float* __restrict__ ginB,
              const float* __restrict__ sm, u32* __restrict__ maxs,
              int layer, int Nn, u16* __restrict__ out)
{
  __shared__ __align__(16) u16 Bls0[128*128];   // 32KB
  __shared__ __align__(16) u16 Bls1[128*128];   // 32KB
  __shared__ float mred[4];
  int tid = threadIdx.x;
  int lane = tid & 63, wave = tid >> 6;
  int m0 = wave*16, mbase = blockIdx.x*64;
  int quad = lane >> 4, lr = lane & 15;
  float w0 = sm[layer*4+0], w1 = sm[layer*4+1], w2 = sm[layer*4+2], w3 = sm[layer*4+3];
  const u16* gcnWb = wsb + (size_t)(1  + layer)*16384;
  const u16* WsWb  = wsb + (size_t)(4  + layer)*16384;
  const u16* WnWb  = wsb + (size_t)(7  + layer)*16384;
  const u16* ginWb = wsb + (size_t)(10 + layer)*16384;
  const u16* gatWb = wsb + (size_t)(13 + layer)*16384;

  // A-fragment addressing (producer's swizzled layout): row mbase+m0+lr,
  // chunk ((ks*4+quad)^lr).
  int arow = mbase + m0 + lr; if (arow >= Nn) arow = Nn - 1;
  size_t abase = (size_t)arow * HD;
  int co[4];
  #pragma unroll
  for (int ks = 0; ks < 4; ks++) co[ks] = ((ks*4 + quad) ^ lr) * 8;

  f32x4 mix[8];
  f32x4 acc[8];
  float b0r[4];
  #pragma unroll
  for (int r=0;r<4;r++){
    int grow = mbase + m0 + quad*4 + r;
    b0r[r] = (grow < Nn) ? b0[grow] : 0.f;
  }

  short8 a0[4], a1[4];
  // prologue: stage B(op0) + prefetch A(op0)=Qb and A(op1)=X
  stageB_async(Bls0, gcnWb, tid);
  #pragma unroll
  for (int ks=0;ks<4;ks++) a0[ks] = *(const short8*)(Qb + abase + co[ks]);
  #pragma unroll
  for (int ks=0;ks<4;ks++) a1[ks] = *(const short8*)(X + abase + co[ks]);
  __syncthreads();                              // B0 resident

  // ---- op0: GCN (A=Qb, B=Bls0) ----
  stageB_async(Bls1, WsWb, tid);                // issue B1 early
  #pragma unroll
  for (int ct=0;ct<8;ct++) acc[ct] = (f32x4){0.f,0.f,0.f,0.f};
  mfma_regA(a0, Bls0, lane, acc);
  #pragma unroll
  for (int ks=0;ks<4;ks++) a0[ks] = *(const short8*)(Pm + abase + co[ks]);  // prefetch op2 A
  {
    float gb[8];
    #pragma unroll
    for (int ct=0;ct<8;ct++) gb[ct] = gcnB[layer*HD + ct*16+lr];
    #pragma unroll
    for (int ct=0;ct<8;ct++)
      #pragma unroll
      for (int r=0;r<4;r++)
        mix[ct][r] = w0 * eluf(acc[ct][r] + b0r[r]*gb[ct]);
  }
  __syncthreads();                              // B1 resident; Bls0 free

  // ---- op1: SAGE self (A=X, B=Bls1) ----
  stageB_async(Bls0, WnWb, tid);                // issue B2 early
  #pragma unroll
  for (int ct=0;ct<8;ct++) acc[ct] = (f32x4){0.f,0.f,0.f,0.f};
  mfma_regA(a1, Bls1, lane, acc);
  #pragma unroll
  for (int ks=0;ks<4;ks++) a1[ks] = *(const short8*)(Gb + abase + co[ks]);  // prefetch op3 A
  __syncthreads();                              // B2 resident; Bls1 free

  // ---- op2: SAGE neighbor (A=Pm, B=Bls0), accumulate into same acc ----
  stageB_async(Bls1, ginWb, tid);               // issue B3 early
  mfma_regA(a0, Bls0, lane, acc);
  #pragma unroll
  for (int ks=0;ks<4;ks++) a0[ks] = *(const short8*)(Rb + abase + co[ks]);  // prefetch op4 A
  #pragma unroll
  for (int ct=0;ct<8;ct++)
    #pragma unroll
    for (int r=0;r<4;r++)
      mix[ct][r] += w1 * eluf(acc[ct][r]);
  __syncthreads();                              // B3 resident; Bls0 free

  // ---- op3: GIN (A=Gb, B=Bls1) ----
  stageB_async(Bls0, gatWb, tid);               // issue B4 early
  #pragma unroll
  for (int ct=0;ct<8;ct++) acc[ct] = (f32x4){0.f,0.f,0.f,0.f};
  mfma_regA(a1, Bls1, lane, acc);
  {
    float gib[8];
    #pragma unroll
    for (int ct=0;ct<8;ct++) gib[ct] = ginB[layer*HD + ct*16+lr];
    #pragma unroll
    for (int ct=0;ct<8;ct++)
      #pragma unroll
      for (int r=0;r<4;r++)
        mix[ct][r] += w2 * eluf(acc[ct][r] + gib[ct]);
  }
  __syncthreads();                              // B4 resident

  // ---- op4: GAT (A=Rb, B=Bls0) ----
  #pragma unroll
  for (int ct=0;ct<8;ct++) acc[ct] = (f32x4){0.f,0.f,0.f,0.f};
  mfma_regA(a0, Bls0, lane, acc);
  #pragma unroll
  for (int ct=0;ct<8;ct++)
    #pragma unroll
    for (int r=0;r<4;r++)
      mix[ct][r] = sane(mix[ct][r] + w3 * eluf(acc[ct][r]));

  // ---- store swizzled ----
  #pragma unroll
  for (int ct=0;ct<8;ct++){
    int c2 = ct*2 + (lr >> 3);
    #pragma unroll
    for (int r=0;r<4;r++){
      int grow = mbase + m0 + quad*4 + r;
      if (grow < Nn) out[(size_t)grow*HD + (c2 ^ (grow & 15))*8 + (lr & 7)] = f2b(mix[ct][r]);
    }
  }
  // ---- epilogue: s,d for next layer + global maxS ----
  if (layer < 2){
    const float* wsv = sm + 32  + (layer+1)*128;
    const float* wdv = sm + 416 + (layer+1)*128;
    float sp[4] = {0.f,0.f,0.f,0.f}, dp[4] = {0.f,0.f,0.f,0.f};
    #pragma unroll
    for (int ct=0;ct<8;ct++){
      float wsc = wsv[ct*16+lr], wdc = wdv[ct*16+lr];
      #pragma unroll
      for (int r=0;r<4;r++){
        sp[r] = fmaf(mix[ct][r], wsc, sp[r]);
        dp[r] = fmaf(mix[ct][r], wdc, dp[r]);
      }
    }
    #pragma unroll
    for (int off=1; off<16; off<<=1)
      #pragma unroll
      for (int r=0;r<4;r++){ sp[r] += __shfl_xor(sp[r], off); dp[r] += __shfl_xor(dp[r], off); }
    float ms = -3.4e38f;
    #pragma unroll
    for (int r=0;r<4;r++){
      int grow = mbase + m0 + quad*4 + r;
      if (grow < Nn){
        ms = fmaxf(ms, sp[r]);
        if (lr == 0) *(float2*)&nd[grow] = make_float2(sp[r], dp[r]);
      }
    }
    ms = fmaxf(ms, __shfl_xor(ms, 16));
    ms = fmaxf(ms, __shfl_xor(ms, 32));
    if (lane == 0) mred[wave] = ms;
    __syncthreads();
    if (tid == 0){
      float m = fmaxf(fmaxf(mred[0],mred[1]), fmaxf(mred[2],mred[3]));
      atomicMax(maxs + layer + 1, fenc(m));
    }
  }
}

// ------- classifier with fused skip/layer-agg (inputs swizzled) ----------
__global__ __launch_bounds__(256)
void k_nc(const u16* __restrict__ X1, const u16* __restrict__ X2, const u16* __restrict__ X3,
          const float* __restrict__ W, const float* __restrict__ bias,
          const float* __restrict__ sm, int Nn, float* __restrict__ out)
{
  __shared__ __align__(16) u16 xs[32*136];
  __shared__ __align__(16) float wn[40*132];
  __shared__ float bs[40];
  int t = threadIdx.x;
  int nb = blockIdx.x*32;
  float c1 = sm[12], c2 = sm[13], la0 = sm[14], la1 = sm[15], la2 = sm[16];
  #pragma unroll
  for (int i = 0; i < 2; i++){
    int chunk = t + 256*i;
    int r = chunk >> 4, c = chunk & 15;
    uint4 v = {0u,0u,0u,0u};
    int gr = nb + r;
    if (gr < Nn){
      size_t o = (size_t)gr*HD + ((c ^ (gr & 15))*8);
      uint4 u1 = *(const uint4*)(X1 + o);
      uint4 u2 = *(const uint4*)(X2 + o);
      uint4 u3 = *(const uint4*)(X3 + o);
      u32* u1p = (u32*)&u1; u32* u2p = (u32*)&u2; u32* u3p = (u32*)&u3; u32* vp = (u32*)&v;
      #pragma unroll
      for (int k = 0; k < 4; k++){
        float o0, o1;
        {
          float a1 = lo2f(u1p[k]), a2 = lo2f(u2p[k]), a3 = lo2f(u3p[k]);
          float t0 = a3, t1 = c1*a1, t2 = c2*a2;
          float smm = t0 + t1 + t2;
          float mx = fmaxf(fmaxf(t0,t1),t2);
          o0 = la0*reluf(mx) + la1*reluf(smm*(1.f/3.f)) + la2*reluf(smm);
        }
        {
          float a1 = hi2f(u1p[k]), a2 = hi2f(u2p[k]), a3 = hi2f(u3p[k]);
          float t0 = a3, t1 = c1*a1, t2 = c2*a2;
          float smm = t0 + t1 + t2;
          float mx = fmaxf(fmaxf(t0,t1),t2);
          o1 = la0*reluf(mx) + la1*reluf(smm*(1.f/3.f)) + la2*reluf(smm);
        }
        vp[k] = pack2(sane(o0), sane(o1));
      }
    }
    *(uint4*)(xs + r*136 + c*8) = v;
  }
  #pragma unroll
  for (int i = 0; i < 5; i++){
    int chunk = t + 256*i;
    int r = chunk >> 5, c = chunk & 31;
    *(float4*)(wn + r*132 + c*4) = *(const float4*)(W + r*HD + c*4);
  }
  if (t < 40) bs[t] = bias[t];
  __syncthreads();
  int nl = t >> 3, cg = t & 7;
  float acc[5];
  #pragma unroll
  for (int j = 0; j < 5; j++) acc[j] = bs[cg + 8*j];
  for (int k = 0; k < 128; k++){
    float xv = b2f(xs[nl*136 + k]);
    #pragma unroll
    for (int j = 0; j < 5; j++)
      acc[j] = fmaf(xv, wn[(cg + 8*j)*132 + k], acc[j]);
  }
  int gr = nb + nl;
  if (gr < Nn){
    #pragma unroll
    for (int j = 0; j < 5; j++)
      out[(size_t)gr*40 + cg + 8*j] = sane(acc[j]);
  }
}

// ---------------- host ----------------
extern "C" void kernel_launch(void* const* d_in, const int* in_sizes, int n_in,
                              void* d_out, int out_size, void* d_ws, size_t ws_size,
                              hipStream_t stream)
{
  (void)n_in; (void)out_size; (void)ws_size;
  const int N = in_sizes[0] / HD;
  const int E = in_sizes[1] / 2;
  const float* x      = (const float*)d_in[0];
  const int*   ei     = (const int*)d_in[1];
  const float* na_a   = (const float*)d_in[2];
  const float* sc_a   = (const float*)d_in[3];
  const float* la_a   = (const float*)d_in[4];
  const float* lin1W  = (const float*)d_in[5];
  const float* lin1b  = (const float*)d_in[6];
  const float* gcnW   = (const float*)d_in[7];
  const float* gcnB   = (const float*)d_in[8];
  const float* sageWs = (const float*)d_in[9];
  const float* sageWn = (const float*)d_in[10];
  const float* ginW   = (const float*)d_in[11];
  const float* ginB   = (const float*)d_in[12];
  const float* ginE   = (const float*)d_in[13];
  const float* gatW   = (const float*)d_in[14];
  const float* gatAs  = (const float*)d_in[15];
  const float* gatAd  = (const float*)d_in[16];
  const float* ncW    = (const float*)d_in[17];
  const float* ncB    = (const float*)d_in[18];

  char* base = (char*)d_ws;
  size_t off = 0;
  auto alloc = [&](size_t b) -> void* {
    void* p = base + off;
    off += (b + 255) & ~(size_t)255;
    return p;
  };
  const int NB  = (N + 1023) / 1024;       // 1024-node scan blocks
  const int B   = (N + 255) >> 8;          // 256-node edge buckets (<=256)
  const int nbe = (E + ETILE - 1) / ETILE; // edge tiles
  float*  smalls = (float*)alloc(4096);
  u32*    maxs   = (u32*)alloc(256);
  int*    cnt    = (int*)alloc((size_t)N*4);
  int*    rowptr = (int*)alloc(((size_t)N+1)*4);
  int*    bsum   = (int*)alloc(4096);
  int*    boffs  = (int*)alloc(4096);
  int*    bh     = (int*)alloc((size_t)NB*256*4);
  int*    perm   = (int*)alloc((size_t)N*4);
  int*    eh     = (int*)alloc((size_t)nbe*256*4);
  int*    btot   = (int*)alloc(1024);
  int*    bbase  = (int*)alloc(1040);
  float4* nd     = (float4*)alloc((size_t)N*16);
  float*  b0     = (float*)alloc((size_t)N*4);
  int*    csr    = (int*)alloc((size_t)E*4);
  u16*    wsb    = (u16*)alloc((size_t)16*16384*2);
  u16*    xh     = (u16*)alloc((size_t)N*HD*2);
  u16*    x1     = (u16*)alloc((size_t)N*HD*2);
  u16*    x2     = (u16*)alloc((size_t)N*HD*2);
  u16*    Qb     = (u16*)alloc((size_t)N*HD*2);
  u16*    Pm     = (u16*)alloc((size_t)N*HD*2);
  u16*    Gb     = (u16*)alloc((size_t)N*HD*2);
  u16*    Rb     = (u16*)alloc((size_t)N*HD*2);
  // ebuf (E*8 = 6.4MB) aliases Qb (12.8MB): k_bfill completes before k_agg
  // first writes Qb (stream-ordered), so no overlap in lifetime.
  int2*   ebuf   = (int2*)Qb;

  k_small<<<1,128,0,stream>>>(na_a, sc_a, la_a, gatW, gatAs, gatAd, ginE, smalls, maxs);
  k_wcvt<<<128,256,0,stream>>>(lin1W, gcnW, sageWs, sageWn, ginW, gatW, wsb);
  // ---- CSR build: bucketed counting sort, zero global fine-grained atomics
  k_ehist<<<nbe,256,0,stream>>>(ei, E, eh);
  k_escan<<<B,256,0,stream>>>(eh, nbe, btot);
  k_bscan<<<1,256,0,stream>>>(btot, B, E, bbase);
  k_escat<<<nbe,256,0,stream>>>(ei, E, B, eh, bbase, ebuf);
  k_bcount<<<B,256,0,stream>>>(ebuf, bbase, N, cnt);
  k_histblk<<<NB,256,0,stream>>>(cnt, N, bh);
  k_hsscan<<<1,256,0,stream>>>(bh, NB);
  k_permscat<<<NB,256,0,stream>>>(cnt, N, bh, perm);
  k_scan1<<<NB,256,0,stream>>>(cnt, N, bsum);
  k_scan2<<<1,1024,0,stream>>>(bsum, NB, boffs, rowptr, N);
  k_scan3<<<NB,256,0,stream>>>(cnt, boffs, N, rowptr, nd);
  k_bfill<<<B,256,0,stream>>>(ebuf, bbase, rowptr, N, csr);
  int gbl64 = (N + 63)/64;
  k_gemm1<<<gbl64,256,0,stream>>>(x, wsb, lin1b, smalls, nd, maxs, N, xh);
  const u16* xc = xh;
  u16* outs[3] = {x1, x2, xh};
  int abl = (N + 15)/16;
  for (int l = 0; l < 3; l++){
    k_agg<<<abl,256,0,stream>>>(xc, rowptr, csr, perm, nd, smalls, maxs, l, N, Qb, Pm, Gb, Rb, b0);
    k_layer3<<<gbl64,256,0,stream>>>(xc, Qb, Pm, Gb, Rb, nd, b0, wsb,
                                     gcnB, ginB, smalls, maxs, l, N, outs[l]);
    xc = outs[l];
  }
  int ncbl = (N + 31)/32;
  k_nc<<<ncbl,256,0,stream>>>(x1, x2, xh, ncW, ncB, smalls, N, (float*)d_out);
}

// Round 6
// 419.624 us; speedup vs baseline: 1.2203x; 1.0449x over previous
//
#include <hip/hip_runtime.h>
#include <hip/hip_bf16.h>

typedef unsigned short u16;
typedef unsigned int u32;
typedef __attribute__((ext_vector_type(8))) short short8;
typedef __attribute__((ext_vector_type(4))) float f32x4;
typedef __attribute__((ext_vector_type(2))) float f32x2;

#define HD 128
#define ETILE 2048

__device__ inline float b2f(u16 u){ u32 v = ((u32)u) << 16; return __uint_as_float(v); }
__device__ inline u16 f2b(float f){
  u32 u = __float_as_uint(f);
  u32 r = (u + 0x7fffu + ((u >> 16) & 1u)) >> 16;
  return (u16)r;
}
// packed f32x2 -> bf16x2 via HW convert
__device__ inline u32 pack2(float a, float b){
  __hip_bfloat162 h = __float22bfloat162_rn(make_float2(a, b));
  union { __hip_bfloat162 h; u32 u; } c; c.h = h; return c.u;
}
__device__ inline float lo2f(u32 w){ return b2f((u16)(w & 0xffff)); }
__device__ inline float hi2f(u32 w){ return b2f((u16)(w >> 16)); }
__device__ inline float eluf(float x){ return x > 0.f ? x : __expf(x) - 1.f; }
__device__ inline float reluf(float x){ return x > 0.f ? x : 0.f; }
__device__ inline float sane(float x){
  if (!(x == x)) return 0.f;
  return fminf(fmaxf(x, -1e30f), 1e30f);
}
// monotone float<->u32 encoding for atomicMax on signed floats
__device__ inline u32 fenc(float f){ u32 u = __float_as_uint(f); return (u & 0x80000000u) ? ~u : (u | 0x80000000u); }
__device__ inline float fdec(u32 u){ return __uint_as_float((u & 0x80000000u) ? (u & 0x7fffffffu) : ~u); }
// async 16B global->LDS
__device__ __forceinline__ void async16(const u16* g, u16* l){
  __builtin_amdgcn_global_load_lds((const __attribute__((address_space(1))) void*)g,
                                   (__attribute__((address_space(3))) void*)l, 16, 0, 0);
}
// per-lane row-scalar ops on bf16x8 A fragments (A row is lane-uniform)
__device__ __forceinline__ short8 scale8(short8 v, float s){
  union { short8 s8; u32 u[4]; } in, out;
  in.s8 = v;
  #pragma unroll
  for (int i = 0; i < 4; i++)
    out.u[i] = pack2(lo2f(in.u[i])*s, hi2f(in.u[i])*s);
  return out.s8;
}
__device__ __forceinline__ short8 comb8(short8 x, short8 p, float e1){
  union { short8 s8; u32 u[4]; } ux, up, out;
  ux.s8 = x; up.s8 = p;
  #pragma unroll
  for (int i = 0; i < 4; i++)
    out.u[i] = pack2(fmaf(e1, lo2f(ux.u[i]), lo2f(up.u[i])),
                     fmaf(e1, hi2f(ux.u[i]), hi2f(up.u[i])));
  return out.s8;
}

// ---------------- small precompute ----------------
__global__ void k_small(const float* __restrict__ na_a, const float* __restrict__ sc_a,
                        const float* __restrict__ la_a, const float* __restrict__ gatW,
                        const float* __restrict__ gat_as, const float* __restrict__ gat_ad,
                        const float* __restrict__ gin_eps, float* __restrict__ sm,
                        u32* __restrict__ maxs)
{
  int t = threadIdx.x;
  if (t < 3) maxs[t] = 0u;
  if (t == 0){
    for (int l = 0; l < 3; l++){
      float a[4]; float mx = -1e30f;
      for (int i = 0; i < 4; i++){ a[i] = na_a[l*4+i]; mx = fmaxf(mx, a[i]); }
      float ssum = 0.f;
      for (int i = 0; i < 4; i++){ a[i] = __expf(a[i]-mx); ssum += a[i]; }
      for (int i = 0; i < 4; i++) sm[l*4+i] = a[i]/ssum;
    }
    for (int r = 0; r < 2; r++){
      float a0 = sc_a[r*2], a1 = sc_a[r*2+1];
      float mx = fmaxf(a0,a1);
      float e0 = __expf(a0-mx), e1 = __expf(a1-mx);
      sm[12+r] = e1/(e0+e1);
    }
    {
      float a0=la_a[0], a1=la_a[1], a2=la_a[2];
      float mx = fmaxf(fmaxf(a0,a1),a2);
      float e0=__expf(a0-mx), e1=__expf(a1-mx), e2=__expf(a2-mx);
      float ssum = e0+e1+e2;
      sm[14]=e0/ssum; sm[15]=e1/ssum; sm[16]=e2/ssum;
    }
    for (int l=0;l<3;l++) sm[17+l] = 1.f + gin_eps[l];
  }
  if (t < 128){
    for (int l=0;l<3;l++){
      float a1=0.f, a2=0.f;
      for (int k=0;k<128;k++){
        float wv = gatW[l*16384 + k*128 + t];
        a1 = fmaf(wv, gat_as[l*128+k], a1);
        a2 = fmaf(wv, gat_ad[l*128+k], a2);
      }
      sm[32  + l*128 + t] = a1;
      sm[416 + l*128 + t] = a2;
    }
  }
}

// -------- weight pre-conversion f32 -> bf16, PRE-SWIZZLED chunk order -------
__device__ __forceinline__ uint4 cvt8(const float* __restrict__ p){
  float4 v0 = *(const float4*)p;
  float4 v1 = *(const float4*)(p + 4);
  uint4 o;
  o.x = pack2(v0.x, v0.y);
  o.y = pack2(v0.z, v0.w);
  o.z = pack2(v1.x, v1.y);
  o.w = pack2(v1.z, v1.w);
  return o;
}
__global__ void k_wcvt(const float* __restrict__ lin1W, const float* __restrict__ gcnW,
                       const float* __restrict__ Ws, const float* __restrict__ Wn,
                       const float* __restrict__ ginW, const float* __restrict__ gatW,
                       u16* __restrict__ wsb)
{
  int i = blockIdx.x*256 + threadIdx.x;
  if (i >= 32768) return;
  int m = i >> 11;
  int j = i & 2047;
  int r = j >> 4, c = j & 15;
  const float* src;
  if (m == 0)       src = lin1W;
  else if (m < 4)   src = gcnW + (m-1)*16384;
  else if (m < 7)   src = Ws   + (m-4)*16384;
  else if (m < 10)  src = Wn   + (m-7)*16384;
  else if (m < 13)  src = ginW + (m-10)*16384;
  else              src = gatW + (m-13)*16384;
  int dj = r*16 + (c ^ (r & 15));
  *(uint4*)(wsb + ((size_t)m*2048 + dj)*8) = cvt8(src + r*HD + c*8);
}

// =============== CSR build via bucketed counting sort of edges =============
// R11 post-mortem: no global fine-grained scatter/atomic on random addresses.
// All fine-grained work is LDS; all global writes are runs.

// pass 1: per-tile bucket histogram (LDS), coalesced write of eh[tile][bucket]
__global__ void k_ehist(const int* __restrict__ ei, int E, int* __restrict__ eh){
  __shared__ int h[256];
  int t = threadIdx.x, b = blockIdx.x;
  h[t] = 0; __syncthreads();
  int base = b*ETILE;
  #pragma unroll
  for (int r = 0; r < ETILE/256; r++){
    int e = base + r*256 + t;
    if (e < E) atomicAdd(&h[ei[E + e] >> 8], 1);
  }
  __syncthreads();
  eh[b*256 + t] = h[t];
}
// pass 2a: per-bucket exclusive scan over tiles (block per bucket), in place
__global__ void k_escan(int* __restrict__ eh, int nblk, int* __restrict__ btot){
  __shared__ int s[256];
  int b = blockIdx.x, t = threadIdx.x;
  int carry = 0;
  int rounds = (nblk + 255)/256;
  for (int r = 0; r < rounds; r++){
    int i = r*256 + t;
    int v = (i < nblk) ? eh[i*256 + b] : 0;
    s[t] = v; __syncthreads();
    for (int off = 1; off < 256; off <<= 1){
      int a = (t >= off) ? s[t - off] : 0;
      __syncthreads();
      s[t] += a;
      __syncthreads();
    }
    if (i < nblk) eh[i*256 + b] = s[t] - v + carry;
    carry += s[255];
    __syncthreads();
  }
  if (t == 0) btot[b] = carry;
}
// pass 2b: bucket bases (single block; B <= 256)
__global__ void k_bscan(const int* __restrict__ btot, int B, int E, int* __restrict__ bbase){
  __shared__ int s[256];
  int t = threadIdx.x;
  int v = (t < B) ? btot[t] : 0;
  s[t] = v; __syncthreads();
  for (int off = 1; off < 256; off <<= 1){
    int a = (t >= off) ? s[t - off] : 0;
    __syncthreads();
    s[t] += a;
    __syncthreads();
  }
  if (t < B) bbase[t] = s[t] - v;
  if (t == 0) bbase[B] = E;
}
// pass 3: scatter (src,dst) records bucket-grouped
__global__ void k_escat(const int* __restrict__ ei, int E, int B,
                        const int* __restrict__ eh, const int* __restrict__ bbase,
                        int2* __restrict__ ebuf){
  __shared__ int cur[256];
  int t = threadIdx.x, b = blockIdx.x;
  cur[t] = (t < B) ? bbase[t] + eh[b*256 + t] : 0;
  __syncthreads();
  int base = b*ETILE;
  #pragma unroll
  for (int r = 0; r < ETILE/256; r++){
    int e = base + r*256 + t;
    if (e < E){
      int sv = ei[e], dv = ei[E + e];
      int p = atomicAdd(&cur[dv >> 8], 1);
      ebuf[p] = make_int2(sv, dv);
    }
  }
}
// pass 4: per-bucket per-node degree count (LDS), coalesced cnt write
__global__ void k_bcount(const int2* __restrict__ ebuf, const int* __restrict__ bbase,
                         int Nn, int* __restrict__ cnt){
  __shared__ int c[256];
  int t = threadIdx.x, b = blockIdx.x;
  c[t] = 0; __syncthreads();
  int beg = bbase[b], end2 = bbase[b+1];
  for (int i = beg + t; i < end2; i += 256)
    atomicAdd(&c[ebuf[i].y & 255], 1);
  __syncthreads();
  int node = b*256 + t;
  if (node < Nn) cnt[node] = c[t];
}
// pass 5: fill csr; LDS cursors seeded from rowptr
__global__ void k_bfill(const int2* __restrict__ ebuf, const int* __restrict__ bbase,
                        const int* __restrict__ rowptr, int Nn, int* __restrict__ csr){
  __shared__ int cu[256];
  int t = threadIdx.x, b = blockIdx.x;
  int node = b*256 + t;
  cu[t] = (node < Nn) ? rowptr[node] : 0;
  __syncthreads();
  int beg = bbase[b], end2 = bbase[b+1];
  for (int i = beg + t; i < end2; i += 256){
    int2 ed = ebuf[i];
    int p = atomicAdd(&cu[ed.y & 255], 1);
    csr[p] = ed.x;
  }
}

// ---------------- rowptr scans ----------------
__global__ void k_scan1(const int* __restrict__ cnt, int Nn, int* __restrict__ bsum){
  __shared__ int red[256];
  int b = blockIdx.x, t = threadIdx.x;
  int base = b*1024 + t*4;
  int s = 0;
  #pragma unroll
  for (int k = 0; k < 4; k++){ int i = base + k; if (i < Nn) s += cnt[i]; }
  red[t] = s; __syncthreads();
  for (int off = 128; off; off >>= 1){
    if (t < off) red[t] += red[t + off];
    __syncthreads();
  }
  if (t == 0) bsum[b] = red[0];
}

__global__ void k_scan2(const int* __restrict__ bsum, int nb,
                        int* __restrict__ boffs, int* __restrict__ rowptr, int Nn){
  __shared__ int sc[1024];
  int t = threadIdx.x;
  int own = (t < nb) ? bsum[t] : 0;
  sc[t] = own;
  __syncthreads();
  for (int off = 1; off < 1024; off <<= 1){
    int add = (t >= off) ? sc[t - off] : 0;
    __syncthreads();
    sc[t] += add;
    __syncthreads();
  }
  if (t < nb) boffs[t] = sc[t] - own;
  if (t == 1023) rowptr[Nn] = sc[1023];
}

__global__ void k_scan3(const int* __restrict__ cnt, const int* __restrict__ boffs, int Nn,
                        int* __restrict__ rowptr, float4* __restrict__ nd){
  __shared__ int red[256];
  int b = blockIdx.x, t = threadIdx.x;
  int base = b*1024 + t*4;
  int c[4]; int s = 0;
  #pragma unroll
  for (int k = 0; k < 4; k++){ int i = base + k; c[k] = (i < Nn) ? cnt[i] : 0; s += c[k]; }
  red[t] = s; __syncthreads();
  for (int off = 1; off < 256; off <<= 1){
    int add = (t >= off) ? red[t - off] : 0;
    __syncthreads();
    red[t] += add;
    __syncthreads();
  }
  int run = red[t] - s + boffs[b];
  #pragma unroll
  for (int k = 0; k < 4; k++){
    int i = base + k;
    if (i < Nn){
      rowptr[i] = run;
      float f = (float)c[k];
      nd[i].z = c[k] > 0 ? 1.f/sqrtf(f) : 0.f;   // dis
      nd[i].w = 1.f/fmaxf(f, 1.f);               // dinv
      run += c[k];
    }
  }
}

// ------- degree-binned node permutation, LDS-histogram counting sort -------
// DESCENDING degree: heavy nodes dispatch first (LPT scheduling -> light tail).
__global__ void k_histblk(const int* __restrict__ cnt, int Nn, int* __restrict__ bh){
  __shared__ int h[256];
  int t = threadIdx.x, b = blockIdx.x;
  h[t] = 0; __syncthreads();
  int base = b*1024;
  #pragma unroll
  for (int k = 0; k < 4; k++){
    int i = base + t + k*256;
    if (i < Nn){ int d = cnt[i]; if (d > 255) d = 255; atomicAdd(&h[d], 1); }
  }
  __syncthreads();
  bh[b*256 + t] = h[t];
}
__global__ void k_hsscan(int* __restrict__ bh, int nb){
  __shared__ int tot[256];
  __shared__ int sc[256];
  int t = threadIdx.x;
  int s = 0;
  for (int b = 0; b < nb; b++){
    int v = bh[b*256 + t];
    bh[b*256 + t] = s;
    s += v;
  }
  tot[t] = s;
  int rt = 255 - t;            // position in DESCENDING-degree order
  __syncthreads();
  sc[rt] = tot[t];
  __syncthreads();
  for (int off = 1; off < 256; off <<= 1){
    int a = (rt >= off) ? sc[rt - off] : 0;
    __syncthreads();
    sc[rt] += a;
    __syncthreads();
  }
  int binbase = sc[rt] - tot[t];
  for (int b = 0; b < nb; b++) bh[b*256 + t] += binbase;
}
__global__ void k_permscat(const int* __restrict__ cnt, int Nn,
                           const int* __restrict__ bh, int* __restrict__ perm){
  __shared__ int cur[256];
  int t = threadIdx.x, b = blockIdx.x;
  cur[t] = bh[b*256 + t];
  __syncthreads();
  int base = b*1024;
  #pragma unroll
  for (int k = 0; k < 4; k++){
    int i = base + t + k*256;
    if (i < Nn){
      int d = cnt[i]; if (d > 255) d = 255;
      int p = atomicAdd(&cur[d], 1);
      perm[p] = i;
    }
  }
}

// ------- aggregation: ONE NODE PER 16-LANE GROUP, single pass --------------
// R10: group-per-node; R11: 4-edge software pipeline (latency-bound chain).
// R15: write only 3 buffers — Qb = dis*q, Pb = RAW p-sum, Rb = zinv*r.
// Pm (dinv*p) and Gb ((1+eps)x+p) are derived per-row inside k_layer3 (the
// MFMA A-fragment row is lane-uniform, so row-scalars are per-lane scalars).
// Epilogue no longer reads the node's own X row.
__global__ __launch_bounds__(256)
void k_agg(const u16* __restrict__ X, const int* __restrict__ rowptr, const int* __restrict__ csr,
           const int* __restrict__ perm,
           const float4* __restrict__ nd, const float* __restrict__ sm,
           const u32* __restrict__ maxs, int layer, int Nn,
           u16* __restrict__ Qb, u16* __restrict__ Pb, u16* __restrict__ Rb,
           float* __restrict__ b0)
{
  int tid = threadIdx.x;
  int lane = tid & 63;
  int g = lane >> 4, t = lane & 15;
  int idx = blockIdx.x*16 + (tid >> 6)*4 + g;
  if (idx >= Nn) return;          // group-level divergence; no barriers below
  int wv = perm[idx];
  int beg = rowptr[wv], end = rowptr[wv+1];
  float4 ndw = nd[wv];
  float dval = ndw.y;
  float bnd = fdec(maxs[layer]) + dval;
  float mloc = fmaxf(bnd, 0.2f*bnd);
  f32x2 p2[4], q2[4], r2[4];
  #pragma unroll
  for (int k = 0; k < 4; k++){ p2[k] = (f32x2){0.f,0.f}; q2[k] = (f32x2){0.f,0.f}; r2[k] = (f32x2){0.f,0.f}; }
  float z = 0.f, qd = 0.f;
  int e = beg;
  // ---- 4-edge pipelined main loop ----
  int nsv0=0, nsv1=0, nsv2=0, nsv3=0;
  if (e + 3 < end){ nsv0 = csr[e]; nsv1 = csr[e+1]; nsv2 = csr[e+2]; nsv3 = csr[e+3]; }
  while (e + 3 < end){
    int sv0 = nsv0, sv1 = nsv1, sv2 = nsv2, sv3 = nsv3;
    int en = e + 4;
    if (en + 3 < end){ nsv0 = csr[en]; nsv1 = csr[en+1]; nsv2 = csr[en+2]; nsv3 = csr[en+3]; }
    float4 n0 = nd[sv0], n1 = nd[sv1], n2 = nd[sv2], n3 = nd[sv3];
    uint4 xv0 = *(const uint4*)(X + (size_t)sv0*HD + (t ^ (sv0 & 15))*8);
    uint4 xv1 = *(const uint4*)(X + (size_t)sv1*HD + (t ^ (sv1 & 15))*8);
    uint4 xv2 = *(const uint4*)(X + (size_t)sv2*HD + (t ^ (sv2 & 15))*8);
    uint4 xv3 = *(const uint4*)(X + (size_t)sv3*HD + (t ^ (sv3 & 15))*8);
    float s0 = n0.x + dval, s1 = n1.x + dval, s2 = n2.x + dval, s3 = n3.x + dval;
    float lg0 = fmaxf(s0, 0.2f*s0), lg1 = fmaxf(s1, 0.2f*s1);
    float lg2 = fmaxf(s2, 0.2f*s2), lg3 = fmaxf(s3, 0.2f*s3);
    float ew0 = __expf(lg0 - mloc), ew1 = __expf(lg1 - mloc);
    float ew2 = __expf(lg2 - mloc), ew3 = __expf(lg3 - mloc);
    u32 a0[4] = {xv0.x, xv0.y, xv0.z, xv0.w};
    u32 a1[4] = {xv1.x, xv1.y, xv1.z, xv1.w};
    u32 a2[4] = {xv2.x, xv2.y, xv2.z, xv2.w};
    u32 a3[4] = {xv3.x, xv3.y, xv3.z, xv3.w};
    f32x2 d0 = {n0.z, n0.z}, d1 = {n1.z, n1.z}, d2 = {n2.z, n2.z}, d3 = {n3.z, n3.z};
    f32x2 e0 = {ew0, ew0}, e1v = {ew1, ew1}, e2v = {ew2, ew2}, e3v = {ew3, ew3};
    #pragma unroll
    for (int k = 0; k < 4; k++){
      f32x2 xf0 = {lo2f(a0[k]), hi2f(a0[k])};
      f32x2 xf1 = {lo2f(a1[k]), hi2f(a1[k])};
      f32x2 xf2 = {lo2f(a2[k]), hi2f(a2[k])};
      f32x2 xf3 = {lo2f(a3[k]), hi2f(a3[k])};
      p2[k] += (xf0 + xf1) + (xf2 + xf3);
      q2[k] = __builtin_elementwise_fma(xf0, d0, q2[k]);
      q2[k] = __builtin_elementwise_fma(xf1, d1, q2[k]);
      q2[k] = __builtin_elementwise_fma(xf2, d2, q2[k]);
      q2[k] = __builtin_elementwise_fma(xf3, d3, q2[k]);
      r2[k] = __builtin_elementwise_fma(xf0, e0, r2[k]);
      r2[k] = __builtin_elementwise_fma(xf1, e1v, r2[k]);
      r2[k] = __builtin_elementwise_fma(xf2, e2v, r2[k]);
      r2[k] = __builtin_elementwise_fma(xf3, e3v, r2[k]);
    }
    z += (ew0 + ew1) + (ew2 + ew3);
    qd += (n0.z + n1.z) + (n2.z + n3.z);
    e = en;
  }
  // ---- 2-edge tail ----
  if (e + 1 < end){
    int sv0 = csr[e], sv1 = csr[e+1];
    float4 n0 = nd[sv0], n1 = nd[sv1];
    uint4 xv0 = *(const uint4*)(X + (size_t)sv0*HD + (t ^ (sv0 & 15))*8);
    uint4 xv1 = *(const uint4*)(X + (size_t)sv1*HD + (t ^ (sv1 & 15))*8);
    float s0 = n0.x + dval, s1 = n1.x + dval;
    float lg0 = fmaxf(s0, 0.2f*s0);
    float lg1 = fmaxf(s1, 0.2f*s1);
    float ew0 = __expf(lg0 - mloc), ew1 = __expf(lg1 - mloc);
    u32 a0[4] = {xv0.x, xv0.y, xv0.z, xv0.w};
    u32 a1[4] = {xv1.x, xv1.y, xv1.z, xv1.w};
    f32x2 d0 = {n0.z, n0.z}, d1 = {n1.z, n1.z};
    f32x2 e0 = {ew0, ew0},   e1v = {ew1, ew1};
    #pragma unroll
    for (int k = 0; k < 4; k++){
      f32x2 xf0 = {lo2f(a0[k]), hi2f(a0[k])};
      f32x2 xf1 = {lo2f(a1[k]), hi2f(a1[k])};
      p2[k] += xf0 + xf1;
      q2[k] = __builtin_elementwise_fma(xf0, d0, q2[k]);
      q2[k] = __builtin_elementwise_fma(xf1, d1, q2[k]);
      r2[k] = __builtin_elementwise_fma(xf0, e0, r2[k]);
      r2[k] = __builtin_elementwise_fma(xf1, e1v, r2[k]);
    }
    z += ew0 + ew1; qd += n0.z + n1.z;
    e += 2;
  }
  // ---- 1-edge tail ----
  if (e < end){
    int sv = csr[e];
    float4 n0 = nd[sv];
    uint4 xv = *(const uint4*)(X + (size_t)sv*HD + (t ^ (sv & 15))*8);
    float s = n0.x + dval;
    float lg = fmaxf(s, 0.2f*s);
    float ew = __expf(lg - mloc);
    u32 a0[4] = {xv.x, xv.y, xv.z, xv.w};
    f32x2 d0 = {n0.z, n0.z}, e0 = {ew, ew};
    #pragma unroll
    for (int k = 0; k < 4; k++){
      f32x2 xf = {lo2f(a0[k]), hi2f(a0[k])};
      p2[k] += xf;
      q2[k] = __builtin_elementwise_fma(xf, d0, q2[k]);
      r2[k] = __builtin_elementwise_fma(xf, e0, r2[k]);
    }
    z += ew; qd += n0.z;
  }
  // epilogue: all 16 lanes of the group store their own chunk (4 nodes/wave)
  {
    float disv = ndw.z;
    float zinv = 1.f/(z + 1e-16f);
    int tch = t ^ (wv & 15);
    size_t o = (size_t)wv*HD + tch*8;
    uint4 qo, po, ro;
    u32* qp = (u32*)&qo; u32* pp = (u32*)&po; u32* rp = (u32*)&ro;
    #pragma unroll
    for (int k = 0; k < 4; k++){
      qp[k] = pack2(disv*q2[k].x, disv*q2[k].y);
      pp[k] = pack2(p2[k].x, p2[k].y);                 // RAW sum
      rp[k] = pack2(zinv*r2[k].x, zinv*r2[k].y);
    }
    *(uint4*)(Qb + o) = qo;
    *(uint4*)(Pb + o) = po;
    *(uint4*)(Rb + o) = ro;
    if (t == 0) b0[wv] = disv*qd;
  }
}

// ---------------- MFMA helpers, M=64 tile ----------------
__device__ __forceinline__ void stageB_async(u16* lds, const u16* __restrict__ w, int tid){
  int lane = tid & 63, wave = tid >> 6;
  #pragma unroll
  for (int i = 0; i < 8; i++){
    int cb = wave*64 + 256*i;
    async16(w + (size_t)(cb + lane)*8, lds + (size_t)cb*8);
  }
}
// A from registers (global fragment layout), B from LDS
__device__ __forceinline__ void mfma_regA(const short8 a[4], const u16* Bls,
                                          int lane, f32x4 acc[8]){
  int quad = lane >> 4, lr = lane & 15;
  #pragma unroll
  for (int ks = 0; ks < 4; ks++){
    int q = ks*4 + quad;
    short8 b[8];
    #pragma unroll
    for (int ct = 0; ct < 8; ct++)
      b[ct] = *(const short8*)(Bls + ((ct*16 + lr)*16 + (q ^ lr))*8);
    #pragma unroll
    for (int ct = 0; ct < 8; ct++)
      acc[ct] = __builtin_amdgcn_mfma_f32_16x16x32_bf16(a[ks], b[ct], acc[ct], 0, 0, 0);
  }
}

// ------- lin1 (R15): direct-reg A (f32 load + cvt), single LDS B stage -----
__global__ __launch_bounds__(256,3)
void k_gemm1(const float* __restrict__ A, const u16* __restrict__ Wb, const float* __restrict__ bias,
             const float* __restrict__ sm, float4* __restrict__ nd, u32* __restrict__ maxs,
             int Nn, u16* __restrict__ out)
{
  __shared__ __align__(16) u16 Bls[128*128];
  __shared__ float mred[4];
  int tid = threadIdx.x;
  int lane = tid & 63, wave = tid >> 6;
  int m0 = wave*16, mbase = blockIdx.x*64;
  int quad = lane >> 4, lr = lane & 15;
  stageB_async(Bls, Wb, tid);
  int arowi = mbase + m0 + lr;
  int arow = (arowi < Nn) ? arowi : (Nn - 1);
  short8 a[4];
  #pragma unroll
  for (int ks = 0; ks < 4; ks++){
    int q = ks*4 + quad;
    union { uint4 u; short8 s; } cv;
    cv.u = cvt8(A + (size_t)arow*HD + q*8);
    a[ks] = cv.s;
  }
  f32x4 acc[8];
  #pragma unroll
  for (int ct=0;ct<8;ct++) acc[ct] = (f32x4){0.f,0.f,0.f,0.f};
  __syncthreads();
  mfma_regA(a, Bls, lane, acc);
  #pragma unroll
  for (int ct=0;ct<8;ct++){
    float bc = bias[ct*16+lr];
    #pragma unroll
    for (int r=0;r<4;r++) acc[ct][r] = sane(acc[ct][r] + bc);
  }
  #pragma unroll
  for (int ct=0;ct<8;ct++){
    int c2 = ct*2 + (lr >> 3);
    #pragma unroll
    for (int r=0;r<4;r++){
      int grow = mbase + m0 + quad*4 + r;
      if (grow < Nn) out[(size_t)grow*HD + (c2 ^ (grow & 15))*8 + (lr & 7)] = f2b(acc[ct][r]);
    }
  }
  {
    const float* wsv = sm + 32;
    const float* wdv = sm + 416;
    float sp[4] = {0.f,0.f,0.f,0.f}, dp[4] = {0.f,0.f,0.f,0.f};
    #pragma unroll
    for (int ct=0;ct<8;ct++){
      float wsc = wsv[ct*16+lr], wdc = wdv[ct*16+lr];
      #pragma unroll
      for (int r=0;r<4;r++){
        sp[r] = fmaf(acc[ct][r], wsc, sp[r]);
        dp[r] = fmaf(acc[ct][r], wdc, dp[r]);
      }
    }
    #pragma unroll
    for (int off=1; off<16; off<<=1)
      #pragma unroll
      for (int r=0;r<4;r++){ sp[r] += __shfl_xor(sp[r], off); dp[r] += __shfl_xor(dp[r], off); }
    float ms = -3.4e38f;
    #pragma unroll
    for (int r=0;r<4;r++){
      int grow = mbase + m0 + quad*4 + r;
      if (grow < Nn){
        ms = fmaxf(ms, sp[r]);
        if (lr == 0) *(float2*)&nd[grow] = make_float2(sp[r], dp[r]);
      }
    }
    ms = fmaxf(ms, __shfl_xor(ms, 16));
    ms = fmaxf(ms, __shfl_xor(ms, 32));
    if (lane == 0) mred[wave] = ms;
    __syncthreads();
    if (tid == 0){
      float m = fmaxf(fmaxf(mred[0],mred[1]), fmaxf(mred[2],mred[3]));
      atomicMax(maxs + 0, fenc(m));
    }
  }
}

// ------- fused layer (R15): B dbuf staged one op ahead, A direct-reg.
// Pm/Gb derived in-register: A-fragment rows are lane-uniform, so
// Pm = dinv[row]*Pb is scale8, Gb = (1+eps)X + Pb is comb8 (per-lane scalars).
// One fewer A stream + one fewer k_agg buffer round-trip.
__global__ __launch_bounds__(256,2)
void k_layer3(const u16* __restrict__ X, const u16* __restrict__ Qb,
              const u16* __restrict__ Pb, const u16* __restrict__ Rb,
              float4* __restrict__ nd, const float* __restrict__ b0,
              const u16* __restrict__ wsb,
              const float* __restrict__ gcnB, const float* __restrict__ ginB,
              const float* __restrict__ sm, u32* __restrict__ maxs,
              int layer, int Nn, u16* __restrict__ out)
{
  __shared__ __align__(16) u16 Bls0[128*128];   // 32KB
  __shared__ __align__(16) u16 Bls1[128*128];   // 32KB
  __shared__ float mred[4];
  int tid = threadIdx.x;
  int lane = tid & 63, wave = tid >> 6;
  int m0 = wave*16, mbase = blockIdx.x*64;
  int quad = lane >> 4, lr = lane & 15;
  float w0 = sm[layer*4+0], w1 = sm[layer*4+1], w2 = sm[layer*4+2], w3 = sm[layer*4+3];
  float e1 = sm[17 + layer];
  const u16* gcnWb = wsb + (size_t)(1  + layer)*16384;
  const u16* WsWb  = wsb + (size_t)(4  + layer)*16384;
  const u16* WnWb  = wsb + (size_t)(7  + layer)*16384;
  const u16* ginWb = wsb + (size_t)(10 + layer)*16384;
  const u16* gatWb = wsb + (size_t)(13 + layer)*16384;

  int arowi = mbase + m0 + lr;
  int arow = (arowi < Nn) ? arowi : (Nn - 1);
  size_t abase = (size_t)arow * HD;
  int co[4];
  #pragma unroll
  for (int ks = 0; ks < 4; ks++) co[ks] = ((ks*4 + quad) ^ lr) * 8;
  float dvr = ((const float*)&nd[arow])[3];   // dinv of this lane's A row

  f32x4 mix[8];
  f32x4 acc[8];
  float b0r[4];
  #pragma unroll
  for (int r=0;r<4;r++){
    int grow = mbase + m0 + quad*4 + r;
    b0r[r] = (grow < Nn) ? b0[grow] : 0.f;
  }

  short8 aQ[4], aX[4], aP[4], aR[4], aT[4];
  // prologue
  stageB_async(Bls0, gcnWb, tid);
  #pragma unroll
  for (int ks=0;ks<4;ks++) aQ[ks] = *(const short8*)(Qb + abase + co[ks]);
  #pragma unroll
  for (int ks=0;ks<4;ks++) aX[ks] = *(const short8*)(X + abase + co[ks]);
  __syncthreads();                              // B0 resident

  // ---- op0: GCN (A=Qb, B=Bls0) ----
  stageB_async(Bls1, WsWb, tid);
  #pragma unroll
  for (int ct=0;ct<8;ct++) acc[ct] = (f32x4){0.f,0.f,0.f,0.f};
  mfma_regA(aQ, Bls0, lane, acc);
  #pragma unroll
  for (int ks=0;ks<4;ks++) aP[ks] = *(const short8*)(Pb + abase + co[ks]);
  {
    float gb[8];
    #pragma unroll
    for (int ct=0;ct<8;ct++) gb[ct] = gcnB[layer*HD + ct*16+lr];
    #pragma unroll
    for (int ct=0;ct<8;ct++)
      #pragma unroll
      for (int r=0;r<4;r++)
        mix[ct][r] = w0 * eluf(acc[ct][r] + b0r[r]*gb[ct]);
  }
  __syncthreads();                              // B1 resident; Bls0 free

  // ---- op1: SAGE self (A=X, B=Bls1) ----
  stageB_async(Bls0, WnWb, tid);
  #pragma unroll
  for (int ct=0;ct<8;ct++) acc[ct] = (f32x4){0.f,0.f,0.f,0.f};
  mfma_regA(aX, Bls1, lane, acc);
  #pragma unroll
  for (int ks=0;ks<4;ks++) aR[ks] = *(const short8*)(Rb + abase + co[ks]);
  __syncthreads();                              // B2 resident; Bls1 free

  // ---- op2: SAGE neighbor (A=dinv*Pb, B=Bls0), accumulate into same acc ----
  stageB_async(Bls1, ginWb, tid);
  #pragma unroll
  for (int ks=0;ks<4;ks++) aT[ks] = scale8(aP[ks], dvr);
  mfma_regA(aT, Bls0, lane, acc);
  #pragma unroll
  for (int ct=0;ct<8;ct++)
    #pragma unroll
    for (int r=0;r<4;r++)
      mix[ct][r] += w1 * eluf(acc[ct][r]);
  __syncthreads();                              // B3 resident; Bls0 free

  // ---- op3: GIN (A=(1+eps)X+Pb, B=Bls1) ----
  stageB_async(Bls0, gatWb, tid);
  #pragma unroll
  for (int ks=0;ks<4;ks++) aT[ks] = comb8(aX[ks], aP[ks], e1);
  #pragma unroll
  for (int ct=0;ct<8;ct++) acc[ct] = (f32x4){0.f,0.f,0.f,0.f};
  mfma_regA(aT, Bls1, lane, acc);
  {
    float gib[8];
    #pragma unroll
    for (int ct=0;ct<8;ct++) gib[ct] = ginB[layer*HD + ct*16+lr];
    #pragma unroll
    for (int ct=0;ct<8;ct++)
      #pragma unroll
      for (int r=0;r<4;r++)
        mix[ct][r] += w2 * eluf(acc[ct][r] + gib[ct]);
  }
  __syncthreads();                              // B4 resident

  // ---- op4: GAT (A=Rb, B=Bls0) ----
  #pragma unroll
  for (int ct=0;ct<8;ct++) acc[ct] = (f32x4){0.f,0.f,0.f,0.f};
  mfma_regA(aR, Bls0, lane, acc);
  #pragma unroll
  for (int ct=0;ct<8;ct++)
    #pragma unroll
    for (int r=0;r<4;r++)
      mix[ct][r] = sane(mix[ct][r] + w3 * eluf(acc[ct][r]));

  // ---- store swizzled ----
  #pragma unroll
  for (int ct=0;ct<8;ct++){
    int c2 = ct*2 + (lr >> 3);
    #pragma unroll
    for (int r=0;r<4;r++){
      int grow = mbase + m0 + quad*4 + r;
      if (grow < Nn) out[(size_t)grow*HD + (c2 ^ (grow & 15))*8 + (lr & 7)] = f2b(mix[ct][r]);
    }
  }
  // ---- epilogue: s,d for next layer + global maxS ----
  if (layer < 2){
    const float* wsv = sm + 32  + (layer+1)*128;
    const float* wdv = sm + 416 + (layer+1)*128;
    float sp[4] = {0.f,0.f,0.f,0.f}, dp[4] = {0.f,0.f,0.f,0.f};
    #pragma unroll
    for (int ct=0;ct<8;ct++){
      float wsc = wsv[ct*16+lr], wdc = wdv[ct*16+lr];
      #pragma unroll
      for (int r=0;r<4;r++){
        sp[r] = fmaf(mix[ct][r], wsc, sp[r]);
        dp[r] = fmaf(mix[ct][r], wdc, dp[r]);
      }
    }
    #pragma unroll
    for (int off=1; off<16; off<<=1)
      #pragma unroll
      for (int r=0;r<4;r++){ sp[r] += __shfl_xor(sp[r], off); dp[r] += __shfl_xor(dp[r], off); }
    float ms = -3.4e38f;
    #pragma unroll
    for (int r=0;r<4;r++){
      int grow = mbase + m0 + quad*4 + r;
      if (grow < Nn){
        ms = fmaxf(ms, sp[r]);
        if (lr == 0) *(float2*)&nd[grow] = make_float2(sp[r], dp[r]);
      }
    }
    ms = fmaxf(ms, __shfl_xor(ms, 16));
    ms = fmaxf(ms, __shfl_xor(ms, 32));
    if (lane == 0) mred[wave] = ms;
    __syncthreads();
    if (tid == 0){
      float m = fmaxf(fmaxf(mred[0],mred[1]), fmaxf(mred[2],mred[3]));
      atomicMax(maxs + layer + 1, fenc(m));
    }
  }
}

// ------- classifier with fused skip/layer-agg (inputs swizzled) ----------
__global__ __launch_bounds__(256)
void k_nc(const u16* __restrict__ X1, const u16* __restrict__ X2, const u16* __restrict__ X3,
          const float* __restrict__ W, const float* __restrict__ bias,
          const float* __restrict__ sm, int Nn, float* __restrict__ out)
{
  __shared__ __align__(16) u16 xs[32*136];
  __shared__ __align__(16) float wn[40*132];
  __shared__ float bs[40];
  int t = threadIdx.x;
  int nb = blockIdx.x*32;
  float c1 = sm[12], c2 = sm[13], la0 = sm[14], la1 = sm[15], la2 = sm[16];
  #pragma unroll
  for (int i = 0; i < 2; i++){
    int chunk = t + 256*i;
    int r = chunk >> 4, c = chunk & 15;
    uint4 v = {0u,0u,0u,0u};
    int gr = nb + r;
    if (gr < Nn){
      size_t o = (size_t)gr*HD + ((c ^ (gr & 15))*8);
      uint4 u1 = *(const uint4*)(X1 + o);
      uint4 u2 = *(const uint4*)(X2 + o);
      uint4 u3 = *(const uint4*)(X3 + o);
      u32* u1p = (u32*)&u1; u32* u2p = (u32*)&u2; u32* u3p = (u32*)&u3; u32* vp = (u32*)&v;
      #pragma unroll
      for (int k = 0; k < 4; k++){
        float o0, o1;
        {
          float a1 = lo2f(u1p[k]), a2 = lo2f(u2p[k]), a3 = lo2f(u3p[k]);
          float t0 = a3, t1 = c1*a1, t2 = c2*a2;
          float smm = t0 + t1 + t2;
          float mx = fmaxf(fmaxf(t0,t1),t2);
          o0 = la0*reluf(mx) + la1*reluf(smm*(1.f/3.f)) + la2*reluf(smm);
        }
        {
          float a1 = hi2f(u1p[k]), a2 = hi2f(u2p[k]), a3 = hi2f(u3p[k]);
          float t0 = a3, t1 = c1*a1, t2 = c2*a2;
          float smm = t0 + t1 + t2;
          float mx = fmaxf(fmaxf(t0,t1),t2);
          o1 = la0*reluf(mx) + la1*reluf(smm*(1.f/3.f)) + la2*reluf(smm);
        }
        vp[k] = pack2(sane(o0), sane(o1));
      }
    }
    *(uint4*)(xs + r*136 + c*8) = v;
  }
  #pragma unroll
  for (int i = 0; i < 5; i++){
    int chunk = t + 256*i;
    int r = chunk >> 5, c = chunk & 31;
    *(float4*)(wn + r*132 + c*4) = *(const float4*)(W + r*HD + c*4);
  }
  if (t < 40) bs[t] = bias[t];
  __syncthreads();
  int nl = t >> 3, cg = t & 7;
  float acc[5];
  #pragma unroll
  for (int j = 0; j < 5; j++) acc[j] = bs[cg + 8*j];
  for (int k = 0; k < 128; k++){
    float xv = b2f(xs[nl*136 + k]);
    #pragma unroll
    for (int j = 0; j < 5; j++)
      acc[j] = fmaf(xv, wn[(cg + 8*j)*132 + k], acc[j]);
  }
  int gr = nb + nl;
  if (gr < Nn){
    #pragma unroll
    for (int j = 0; j < 5; j++)
      out[(size_t)gr*40 + cg + 8*j] = sane(acc[j]);
  }
}

// ---------------- host ----------------
extern "C" void kernel_launch(void* const* d_in, const int* in_sizes, int n_in,
                              void* d_out, int out_size, void* d_ws, size_t ws_size,
                              hipStream_t stream)
{
  (void)n_in; (void)out_size; (void)ws_size;
  const int N = in_sizes[0] / HD;
  const int E = in_sizes[1] / 2;
  const float* x      = (const float*)d_in[0];
  const int*   ei     = (const int*)d_in[1];
  const float* na_a   = (const float*)d_in[2];
  const float* sc_a   = (const float*)d_in[3];
  const float* la_a   = (const float*)d_in[4];
  const float* lin1W  = (const float*)d_in[5];
  const float* lin1b  = (const float*)d_in[6];
  const float* gcnW   = (const float*)d_in[7];
  const float* gcnB   = (const float*)d_in[8];
  const float* sageWs = (const float*)d_in[9];
  const float* sageWn = (const float*)d_in[10];
  const float* ginW   = (const float*)d_in[11];
  const float* ginB   = (const float*)d_in[12];
  const float* ginE   = (const float*)d_in[13];
  const float* gatW   = (const float*)d_in[14];
  const float* gatAs  = (const float*)d_in[15];
  const float* gatAd  = (const float*)d_in[16];
  const float* ncW    = (const float*)d_in[17];
  const float* ncB    = (const float*)d_in[18];

  char* base = (char*)d_ws;
  size_t off = 0;
  auto alloc = [&](size_t b) -> void* {
    void* p = base + off;
    off += (b + 255) & ~(size_t)255;
    return p;
  };
  const int NB  = (N + 1023) / 1024;       // 1024-node scan blocks
  const int B   = (N + 255) >> 8;          // 256-node edge buckets (<=256)
  const int nbe = (E + ETILE - 1) / ETILE; // edge tiles
  float*  smalls = (float*)alloc(4096);
  u32*    maxs   = (u32*)alloc(256);
  int*    cnt    = (int*)alloc((size_t)N*4);
  int*    rowptr = (int*)alloc(((size_t)N+1)*4);
  int*    bsum   = (int*)alloc(4096);
  int*    boffs  = (int*)alloc(4096);
  int*    bh     = (int*)alloc((size_t)NB*256*4);
  int*    perm   = (int*)alloc((size_t)N*4);
  int*    eh     = (int*)alloc((size_t)nbe*256*4);
  int*    btot   = (int*)alloc(1024);
  int*    bbase  = (int*)alloc(1040);
  float4* nd     = (float4*)alloc((size_t)N*16);
  float*  b0     = (float*)alloc((size_t)N*4);
  int*    csr    = (int*)alloc((size_t)E*4);
  u16*    wsb    = (u16*)alloc((size_t)16*16384*2);
  u16*    xh     = (u16*)alloc((size_t)N*HD*2);
  u16*    x1     = (u16*)alloc((size_t)N*HD*2);
  u16*    x2     = (u16*)alloc((size_t)N*HD*2);
  u16*    Qb     = (u16*)alloc((size_t)N*HD*2);
  u16*    Pb     = (u16*)alloc((size_t)N*HD*2);
  u16*    Rb     = (u16*)alloc((size_t)N*HD*2);
  // ebuf (E*8 = 6.4MB) aliases Qb (12.8MB): k_bfill completes before k_agg
  // first writes Qb (stream-ordered), so no overlap in lifetime.
  int2*   ebuf   = (int2*)Qb;

  k_small<<<1,128,0,stream>>>(na_a, sc_a, la_a, gatW, gatAs, gatAd, ginE, smalls, maxs);
  k_wcvt<<<128,256,0,stream>>>(lin1W, gcnW, sageWs, sageWn, ginW, gatW, wsb);
  // ---- CSR build: bucketed counting sort, zero global fine-grained atomics
  k_ehist<<<nbe,256,0,stream>>>(ei, E, eh);
  k_escan<<<B,256,0,stream>>>(eh, nbe, btot);
  k_bscan<<<1,256,0,stream>>>(btot, B, E, bbase);
  k_escat<<<nbe,256,0,stream>>>(ei, E, B, eh, bbase, ebuf);
  k_bcount<<<B,256,0,stream>>>(ebuf, bbase, N, cnt);
  k_histblk<<<NB,256,0,stream>>>(cnt, N, bh);
  k_hsscan<<<1,256,0,stream>>>(bh, NB);
  k_permscat<<<NB,256,0,stream>>>(cnt, N, bh, perm);
  k_scan1<<<NB,256,0,stream>>>(cnt, N, bsum);
  k_scan2<<<1,1024,0,stream>>>(bsum, NB, boffs, rowptr, N);
  k_scan3<<<NB,256,0,stream>>>(cnt, boffs, N, rowptr, nd);
  k_bfill<<<B,256,0,stream>>>(ebuf, bbase, rowptr, N, csr);
  int gbl64 = (N + 63)/64;
  k_gemm1<<<gbl64,256,0,stream>>>(x, wsb, lin1b, smalls, nd, maxs, N, xh);
  const u16* xc = xh;
  u16* outs[3] = {x1, x2, xh};
  int abl = (N + 15)/16;
  for (int l = 0; l < 3; l++){
    k_agg<<<abl,256,0,stream>>>(xc, rowptr, csr, perm, nd, smalls, maxs, l, N, Qb, Pb, Rb, b0);
    k_layer3<<<gbl64,256,0,stream>>>(xc, Qb, Pb, Rb, nd, b0, wsb,
                                     gcnB, ginB, smalls, maxs, l, N, outs[l]);
    xc = outs[l];
  }
  int ncbl = (N + 31)/32;
  k_nc<<<ncbl,256,0,stream>>>(x1, x2, xh, ncW, ncB, smalls, N, (float*)d_out);
}

// Round 7
// 410.346 us; speedup vs baseline: 1.2479x; 1.0226x over previous
//
#include <hip/hip_runtime.h>
#include <hip/hip_bf16.h>

typedef unsigned short u16;
typedef unsigned int u32;
typedef __attribute__((ext_vector_type(8))) short short8;
typedef __attribute__((ext_vector_type(4))) float f32x4;
typedef __attribute__((ext_vector_type(2))) float f32x2;

#define HD 128
#define ETILE 2048

__device__ inline float b2f(u16 u){ u32 v = ((u32)u) << 16; return __uint_as_float(v); }
__device__ inline u16 f2b(float f){
  u32 u = __float_as_uint(f);
  u32 r = (u + 0x7fffu + ((u >> 16) & 1u)) >> 16;
  return (u16)r;
}
// packed f32x2 -> bf16x2 via HW convert
__device__ inline u32 pack2(float a, float b){
  __hip_bfloat162 h = __float22bfloat162_rn(make_float2(a, b));
  union { __hip_bfloat162 h; u32 u; } c; c.h = h; return c.u;
}
__device__ inline float lo2f(u32 w){ return b2f((u16)(w & 0xffff)); }
__device__ inline float hi2f(u32 w){ return b2f((u16)(w >> 16)); }
__device__ inline float eluf(float x){ return x > 0.f ? x : __expf(x) - 1.f; }
__device__ inline float reluf(float x){ return x > 0.f ? x : 0.f; }
__device__ inline float sane(float x){
  if (!(x == x)) return 0.f;
  return fminf(fmaxf(x, -1e30f), 1e30f);
}
// monotone float<->u32 encoding for atomicMax on signed floats
__device__ inline u32 fenc(float f){ u32 u = __float_as_uint(f); return (u & 0x80000000u) ? ~u : (u | 0x80000000u); }
__device__ inline float fdec(u32 u){ return __uint_as_float((u & 0x80000000u) ? (u & 0x7fffffffu) : ~u); }
// async 16B global->LDS
__device__ __forceinline__ void async16(const u16* g, u16* l){
  __builtin_amdgcn_global_load_lds((const __attribute__((address_space(1))) void*)g,
                                   (__attribute__((address_space(3))) void*)l, 16, 0, 0);
}
// per-lane row-scalar ops on bf16x8 A fragments (A row is lane-uniform)
__device__ __forceinline__ short8 scale8(short8 v, float s){
  union { short8 s8; u32 u[4]; } in, out;
  in.s8 = v;
  #pragma unroll
  for (int i = 0; i < 4; i++)
    out.u[i] = pack2(lo2f(in.u[i])*s, hi2f(in.u[i])*s);
  return out.s8;
}
__device__ __forceinline__ short8 comb8(short8 x, short8 p, float e1){
  union { short8 s8; u32 u[4]; } ux, up, out;
  ux.s8 = x; up.s8 = p;
  #pragma unroll
  for (int i = 0; i < 4; i++)
    out.u[i] = pack2(fmaf(e1, lo2f(ux.u[i]), lo2f(up.u[i])),
                     fmaf(e1, hi2f(ux.u[i]), hi2f(up.u[i])));
  return out.s8;
}

// -------- weight pre-conversion (+ merged small precompute in block 0) -----
__device__ __forceinline__ uint4 cvt8(const float* __restrict__ p){
  float4 v0 = *(const float4*)p;
  float4 v1 = *(const float4*)(p + 4);
  uint4 o;
  o.x = pack2(v0.x, v0.y);
  o.y = pack2(v0.z, v0.w);
  o.z = pack2(v1.x, v1.y);
  o.w = pack2(v1.z, v1.w);
  return o;
}
// R16: k_small folded into block 0 (saves one dispatch; no ordering hazard —
// sm/maxs are first consumed by k_gemm1/k_agg, launched much later).
__global__ void k_wcvt(const float* __restrict__ lin1W, const float* __restrict__ gcnW,
                       const float* __restrict__ Ws, const float* __restrict__ Wn,
                       const float* __restrict__ ginW, const float* __restrict__ gatW,
                       u16* __restrict__ wsb,
                       const float* __restrict__ na_a, const float* __restrict__ sc_a,
                       const float* __restrict__ la_a, const float* __restrict__ gat_as,
                       const float* __restrict__ gat_ad, const float* __restrict__ gin_eps,
                       float* __restrict__ sm, u32* __restrict__ maxs)
{
  int t = threadIdx.x;
  if (blockIdx.x == 0){
    if (t < 3) maxs[t] = 0u;
    if (t == 0){
      for (int l = 0; l < 3; l++){
        float a[4]; float mx = -1e30f;
        for (int i = 0; i < 4; i++){ a[i] = na_a[l*4+i]; mx = fmaxf(mx, a[i]); }
        float ssum = 0.f;
        for (int i = 0; i < 4; i++){ a[i] = __expf(a[i]-mx); ssum += a[i]; }
        for (int i = 0; i < 4; i++) sm[l*4+i] = a[i]/ssum;
      }
      for (int r = 0; r < 2; r++){
        float a0 = sc_a[r*2], a1 = sc_a[r*2+1];
        float mx = fmaxf(a0,a1);
        float e0 = __expf(a0-mx), e1 = __expf(a1-mx);
        sm[12+r] = e1/(e0+e1);
      }
      {
        float a0=la_a[0], a1=la_a[1], a2=la_a[2];
        float mx = fmaxf(fmaxf(a0,a1),a2);
        float e0=__expf(a0-mx), e1=__expf(a1-mx), e2=__expf(a2-mx);
        float ssum = e0+e1+e2;
        sm[14]=e0/ssum; sm[15]=e1/ssum; sm[16]=e2/ssum;
      }
      for (int l=0;l<3;l++) sm[17+l] = 1.f + gin_eps[l];
    }
    if (t < 128){
      for (int l=0;l<3;l++){
        float a1=0.f, a2=0.f;
        for (int k=0;k<128;k++){
          float wv = gatW[l*16384 + k*128 + t];
          a1 = fmaf(wv, gat_as[l*128+k], a1);
          a2 = fmaf(wv, gat_ad[l*128+k], a2);
        }
        sm[32  + l*128 + t] = a1;
        sm[416 + l*128 + t] = a2;
      }
    }
  }
  int i = blockIdx.x*256 + t;
  if (i >= 32768) return;
  int m = i >> 11;
  int j = i & 2047;
  int r = j >> 4, c = j & 15;
  const float* src;
  if (m == 0)       src = lin1W;
  else if (m < 4)   src = gcnW + (m-1)*16384;
  else if (m < 7)   src = Ws   + (m-4)*16384;
  else if (m < 10)  src = Wn   + (m-7)*16384;
  else if (m < 13)  src = ginW + (m-10)*16384;
  else              src = gatW + (m-13)*16384;
  int dj = r*16 + (c ^ (r & 15));
  *(uint4*)(wsb + ((size_t)m*2048 + dj)*8) = cvt8(src + r*HD + c*8);
}

// =============== CSR build via bucketed counting sort of edges =============
// R11 post-mortem: no global fine-grained scatter/atomic on random addresses.
// All fine-grained work is LDS; all global writes are runs.

// pass 1: per-tile bucket histogram (LDS), coalesced write of eh[tile][bucket]
__global__ void k_ehist(const int* __restrict__ ei, int E, int* __restrict__ eh){
  __shared__ int h[256];
  int t = threadIdx.x, b = blockIdx.x;
  h[t] = 0; __syncthreads();
  int base = b*ETILE;
  #pragma unroll
  for (int r = 0; r < ETILE/256; r++){
    int e = base + r*256 + t;
    if (e < E) atomicAdd(&h[ei[E + e] >> 8], 1);
  }
  __syncthreads();
  eh[b*256 + t] = h[t];
}
// pass 2a: per-bucket exclusive scan over tiles (block per bucket), in place
__global__ void k_escan(int* __restrict__ eh, int nblk, int* __restrict__ btot){
  __shared__ int s[256];
  int b = blockIdx.x, t = threadIdx.x;
  int carry = 0;
  int rounds = (nblk + 255)/256;
  for (int r = 0; r < rounds; r++){
    int i = r*256 + t;
    int v = (i < nblk) ? eh[i*256 + b] : 0;
    s[t] = v; __syncthreads();
    for (int off = 1; off < 256; off <<= 1){
      int a = (t >= off) ? s[t - off] : 0;
      __syncthreads();
      s[t] += a;
      __syncthreads();
    }
    if (i < nblk) eh[i*256 + b] = s[t] - v + carry;
    carry += s[255];
    __syncthreads();
  }
  if (t == 0) btot[b] = carry;
}
// pass 2b: bucket bases (single block; B <= 256)
__global__ void k_bscan(const int* __restrict__ btot, int B, int E, int* __restrict__ bbase){
  __shared__ int s[256];
  int t = threadIdx.x;
  int v = (t < B) ? btot[t] : 0;
  s[t] = v; __syncthreads();
  for (int off = 1; off < 256; off <<= 1){
    int a = (t >= off) ? s[t - off] : 0;
    __syncthreads();
    s[t] += a;
    __syncthreads();
  }
  if (t < B) bbase[t] = s[t] - v;
  if (t == 0) bbase[B] = E;
}
// pass 3: scatter (src,dst) records bucket-grouped
__global__ void k_escat(const int* __restrict__ ei, int E, int B,
                        const int* __restrict__ eh, const int* __restrict__ bbase,
                        int2* __restrict__ ebuf){
  __shared__ int cur[256];
  int t = threadIdx.x, b = blockIdx.x;
  cur[t] = (t < B) ? bbase[t] + eh[b*256 + t] : 0;
  __syncthreads();
  int base = b*ETILE;
  #pragma unroll
  for (int r = 0; r < ETILE/256; r++){
    int e = base + r*256 + t;
    if (e < E){
      int sv = ei[e], dv = ei[E + e];
      int p = atomicAdd(&cur[dv >> 8], 1);
      ebuf[p] = make_int2(sv, dv);
    }
  }
}
// pass 4: per-bucket per-node degree count (LDS), coalesced cnt write
__global__ void k_bcount(const int2* __restrict__ ebuf, const int* __restrict__ bbase,
                         int Nn, int* __restrict__ cnt){
  __shared__ int c[256];
  int t = threadIdx.x, b = blockIdx.x;
  c[t] = 0; __syncthreads();
  int beg = bbase[b], end2 = bbase[b+1];
  for (int i = beg + t; i < end2; i += 256)
    atomicAdd(&c[ebuf[i].y & 255], 1);
  __syncthreads();
  int node = b*256 + t;
  if (node < Nn) cnt[node] = c[t];
}
// pass 5: fill csr; LDS cursors seeded from rowptr
__global__ void k_bfill(const int2* __restrict__ ebuf, const int* __restrict__ bbase,
                        const int* __restrict__ rowptr, int Nn, int* __restrict__ csr){
  __shared__ int cu[256];
  int t = threadIdx.x, b = blockIdx.x;
  int node = b*256 + t;
  cu[t] = (node < Nn) ? rowptr[node] : 0;
  __syncthreads();
  int beg = bbase[b], end2 = bbase[b+1];
  for (int i = beg + t; i < end2; i += 256){
    int2 ed = ebuf[i];
    int p = atomicAdd(&cu[ed.y & 255], 1);
    csr[p] = ed.x;
  }
}

// ------- R16 merged node-preprocessing (saves 3 dispatches) ----------------
// scan1 + histblk: one pass over cnt produces block-sum AND degree histogram.
__global__ void k_scanhist(const int* __restrict__ cnt, int Nn,
                           int* __restrict__ bsum, int* __restrict__ bh){
  __shared__ int red[256];
  __shared__ int h[256];
  int b = blockIdx.x, t = threadIdx.x;
  h[t] = 0; __syncthreads();
  int base = b*1024 + t*4;
  int c[4]; int s = 0;
  #pragma unroll
  for (int k = 0; k < 4; k++){
    int i = base + k;
    c[k] = (i < Nn) ? cnt[i] : 0; s += c[k];
    if (i < Nn){ int d = c[k] > 255 ? 255 : c[k]; atomicAdd(&h[d], 1); }
  }
  red[t] = s;
  __syncthreads();
  bh[b*256 + t] = h[t];                 // histogram final after barrier
  for (int off = 128; off; off >>= 1){
    if (t < off) red[t] += red[t + off];
    __syncthreads();
  }
  if (t == 0) bsum[b] = red[0];
}
// scan2 + hsscan: single 1024-thread block. Barriers kept unconditional
// (memory ops guarded, __syncthreads never under divergent guard).
__global__ void k_scan2h(const int* __restrict__ bsum, int nb,
                         int* __restrict__ boffs, int* __restrict__ rowptr, int Nn,
                         int* __restrict__ bh){
  __shared__ int sc[1024];
  __shared__ int tot[256];
  __shared__ int sc2[256];
  int t = threadIdx.x;
  // ---- scan2: block-sum exclusive scan ----
  int own = (t < nb) ? bsum[t] : 0;
  sc[t] = own;
  __syncthreads();
  for (int off = 1; off < 1024; off <<= 1){
    int add = (t >= off) ? sc[t - off] : 0;
    __syncthreads();
    sc[t] += add;
    __syncthreads();
  }
  if (t < nb) boffs[t] = sc[t] - own;
  if (t == 1023) rowptr[Nn] = sc[1023];
  // ---- hsscan: per-bin prefix over blocks + DESCENDING-degree bin bases ----
  int s = 0;
  if (t < 256){
    for (int b = 0; b < nb; b++){
      int v = bh[b*256 + t];
      bh[b*256 + t] = s;
      s += v;
    }
    tot[t] = s;
  }
  int rt = 255 - t;
  __syncthreads();
  if (t < 256) sc2[rt] = tot[t];
  __syncthreads();
  for (int off = 1; off < 256; off <<= 1){
    int a = (t < 256 && rt >= off) ? sc2[rt - off] : 0;
    __syncthreads();
    if (t < 256) sc2[rt] += a;
    __syncthreads();
  }
  if (t < 256){
    int binbase = sc2[rt] - tot[t];
    for (int b = 0; b < nb; b++) bh[b*256 + t] += binbase;
  }
}
// scan3 + permscat: rowptr/nd AND perm scatter in one pass (cnt read once).
__global__ void k_scan3p(const int* __restrict__ cnt, const int* __restrict__ boffs, int Nn,
                         int* __restrict__ rowptr, float4* __restrict__ nd,
                         const int* __restrict__ bh, int* __restrict__ perm){
  __shared__ int red[256];
  __shared__ int cur[256];
  int b = blockIdx.x, t = threadIdx.x;
  cur[t] = bh[b*256 + t];
  int base = b*1024 + t*4;
  int c[4]; int s = 0;
  #pragma unroll
  for (int k = 0; k < 4; k++){ int i = base + k; c[k] = (i < Nn) ? cnt[i] : 0; s += c[k]; }
  red[t] = s; __syncthreads();
  for (int off = 1; off < 256; off <<= 1){
    int add = (t >= off) ? red[t - off] : 0;
    __syncthreads();
    red[t] += add;
    __syncthreads();
  }
  int run = red[t] - s + boffs[b];
  #pragma unroll
  for (int k = 0; k < 4; k++){
    int i = base + k;
    if (i < Nn){
      rowptr[i] = run;
      float f = (float)c[k];
      nd[i].z = c[k] > 0 ? 1.f/sqrtf(f) : 0.f;   // dis
      nd[i].w = 1.f/fmaxf(f, 1.f);               // dinv
      run += c[k];
      int d = c[k] > 255 ? 255 : c[k];
      int p = atomicAdd(&cur[d], 1);
      perm[p] = i;
    }
  }
}

// ------- aggregation: ONE NODE PER 16-LANE GROUP, single pass --------------
// R10: group-per-node; R11: 4-edge software pipeline (latency-bound chain).
// R15: write only 3 buffers — Qb = dis*q, Pb = RAW p-sum, Rb = zinv*r.
// Pm (dinv*p) and Gb ((1+eps)x+p) are derived per-row inside k_layer3.
// R16 status: FETCH = 8x X matrix (one copy per XCD L2) and the 205MB logical
// gather runs at ~5.5 TB/s effective — at the die-level random-gather
// ceiling; leave structure alone.
__global__ __launch_bounds__(256)
void k_agg(const u16* __restrict__ X, const int* __restrict__ rowptr, const int* __restrict__ csr,
           const int* __restrict__ perm,
           const float4* __restrict__ nd, const float* __restrict__ sm,
           const u32* __restrict__ maxs, int layer, int Nn,
           u16* __restrict__ Qb, u16* __restrict__ Pb, u16* __restrict__ Rb,
           float* __restrict__ b0)
{
  int tid = threadIdx.x;
  int lane = tid & 63;
  int g = lane >> 4, t = lane & 15;
  int idx = blockIdx.x*16 + (tid >> 6)*4 + g;
  if (idx >= Nn) return;          // group-level divergence; no barriers below
  int wv = perm[idx];
  int beg = rowptr[wv], end = rowptr[wv+1];
  float4 ndw = nd[wv];
  float dval = ndw.y;
  float bnd = fdec(maxs[layer]) + dval;
  float mloc = fmaxf(bnd, 0.2f*bnd);
  f32x2 p2[4], q2[4], r2[4];
  #pragma unroll
  for (int k = 0; k < 4; k++){ p2[k] = (f32x2){0.f,0.f}; q2[k] = (f32x2){0.f,0.f}; r2[k] = (f32x2){0.f,0.f}; }
  float z = 0.f, qd = 0.f;
  int e = beg;
  // ---- 4-edge pipelined main loop ----
  int nsv0=0, nsv1=0, nsv2=0, nsv3=0;
  if (e + 3 < end){ nsv0 = csr[e]; nsv1 = csr[e+1]; nsv2 = csr[e+2]; nsv3 = csr[e+3]; }
  while (e + 3 < end){
    int sv0 = nsv0, sv1 = nsv1, sv2 = nsv2, sv3 = nsv3;
    int en = e + 4;
    if (en + 3 < end){ nsv0 = csr[en]; nsv1 = csr[en+1]; nsv2 = csr[en+2]; nsv3 = csr[en+3]; }
    float4 n0 = nd[sv0], n1 = nd[sv1], n2 = nd[sv2], n3 = nd[sv3];
    uint4 xv0 = *(const uint4*)(X + (size_t)sv0*HD + (t ^ (sv0 & 15))*8);
    uint4 xv1 = *(const uint4*)(X + (size_t)sv1*HD + (t ^ (sv1 & 15))*8);
    uint4 xv2 = *(const uint4*)(X + (size_t)sv2*HD + (t ^ (sv2 & 15))*8);
    uint4 xv3 = *(const uint4*)(X + (size_t)sv3*HD + (t ^ (sv3 & 15))*8);
    float s0 = n0.x + dval, s1 = n1.x + dval, s2 = n2.x + dval, s3 = n3.x + dval;
    float lg0 = fmaxf(s0, 0.2f*s0), lg1 = fmaxf(s1, 0.2f*s1);
    float lg2 = fmaxf(s2, 0.2f*s2), lg3 = fmaxf(s3, 0.2f*s3);
    float ew0 = __expf(lg0 - mloc), ew1 = __expf(lg1 - mloc);
    float ew2 = __expf(lg2 - mloc), ew3 = __expf(lg3 - mloc);
    u32 a0[4] = {xv0.x, xv0.y, xv0.z, xv0.w};
    u32 a1[4] = {xv1.x, xv1.y, xv1.z, xv1.w};
    u32 a2[4] = {xv2.x, xv2.y, xv2.z, xv2.w};
    u32 a3[4] = {xv3.x, xv3.y, xv3.z, xv3.w};
    f32x2 d0 = {n0.z, n0.z}, d1 = {n1.z, n1.z}, d2 = {n2.z, n2.z}, d3 = {n3.z, n3.z};
    f32x2 e0 = {ew0, ew0}, e1v = {ew1, ew1}, e2v = {ew2, ew2}, e3v = {ew3, ew3};
    #pragma unroll
    for (int k = 0; k < 4; k++){
      f32x2 xf0 = {lo2f(a0[k]), hi2f(a0[k])};
      f32x2 xf1 = {lo2f(a1[k]), hi2f(a1[k])};
      f32x2 xf2 = {lo2f(a2[k]), hi2f(a2[k])};
      f32x2 xf3 = {lo2f(a3[k]), hi2f(a3[k])};
      p2[k] += (xf0 + xf1) + (xf2 + xf3);
      q2[k] = __builtin_elementwise_fma(xf0, d0, q2[k]);
      q2[k] = __builtin_elementwise_fma(xf1, d1, q2[k]);
      q2[k] = __builtin_elementwise_fma(xf2, d2, q2[k]);
      q2[k] = __builtin_elementwise_fma(xf3, d3, q2[k]);
      r2[k] = __builtin_elementwise_fma(xf0, e0, r2[k]);
      r2[k] = __builtin_elementwise_fma(xf1, e1v, r2[k]);
      r2[k] = __builtin_elementwise_fma(xf2, e2v, r2[k]);
      r2[k] = __builtin_elementwise_fma(xf3, e3v, r2[k]);
    }
    z += (ew0 + ew1) + (ew2 + ew3);
    qd += (n0.z + n1.z) + (n2.z + n3.z);
    e = en;
  }
  // ---- 2-edge tail ----
  if (e + 1 < end){
    int sv0 = csr[e], sv1 = csr[e+1];
    float4 n0 = nd[sv0], n1 = nd[sv1];
    uint4 xv0 = *(const uint4*)(X + (size_t)sv0*HD + (t ^ (sv0 & 15))*8);
    uint4 xv1 = *(const uint4*)(X + (size_t)sv1*HD + (t ^ (sv1 & 15))*8);
    float s0 = n0.x + dval, s1 = n1.x + dval;
    float lg0 = fmaxf(s0, 0.2f*s0);
    float lg1 = fmaxf(s1, 0.2f*s1);
    float ew0 = __expf(lg0 - mloc), ew1 = __expf(lg1 - mloc);
    u32 a0[4] = {xv0.x, xv0.y, xv0.z, xv0.w};
    u32 a1[4] = {xv1.x, xv1.y, xv1.z, xv1.w};
    f32x2 d0 = {n0.z, n0.z}, d1 = {n1.z, n1.z};
    f32x2 e0 = {ew0, ew0},   e1v = {ew1, ew1};
    #pragma unroll
    for (int k = 0; k < 4; k++){
      f32x2 xf0 = {lo2f(a0[k]), hi2f(a0[k])};
      f32x2 xf1 = {lo2f(a1[k]), hi2f(a1[k])};
      p2[k] += xf0 + xf1;
      q2[k] = __builtin_elementwise_fma(xf0, d0, q2[k]);
      q2[k] = __builtin_elementwise_fma(xf1, d1, q2[k]);
      r2[k] = __builtin_elementwise_fma(xf0, e0, r2[k]);
      r2[k] = __builtin_elementwise_fma(xf1, e1v, r2[k]);
    }
    z += ew0 + ew1; qd += n0.z + n1.z;
    e += 2;
  }
  // ---- 1-edge tail ----
  if (e < end){
    int sv = csr[e];
    float4 n0 = nd[sv];
    uint4 xv = *(const uint4*)(X + (size_t)sv*HD + (t ^ (sv & 15))*8);
    float s = n0.x + dval;
    float lg = fmaxf(s, 0.2f*s);
    float ew = __expf(lg - mloc);
    u32 a0[4] = {xv.x, xv.y, xv.z, xv.w};
    f32x2 d0 = {n0.z, n0.z}, e0 = {ew, ew};
    #pragma unroll
    for (int k = 0; k < 4; k++){
      f32x2 xf = {lo2f(a0[k]), hi2f(a0[k])};
      p2[k] += xf;
      q2[k] = __builtin_elementwise_fma(xf, d0, q2[k]);
      r2[k] = __builtin_elementwise_fma(xf, e0, r2[k]);
    }
    z += ew; qd += n0.z;
  }
  // epilogue: all 16 lanes of the group store their own chunk (4 nodes/wave)
  {
    float disv = ndw.z;
    float zinv = 1.f/(z + 1e-16f);
    int tch = t ^ (wv & 15);
    size_t o = (size_t)wv*HD + tch*8;
    uint4 qo, po, ro;
    u32* qp = (u32*)&qo; u32* pp = (u32*)&po; u32* rp = (u32*)&ro;
    #pragma unroll
    for (int k = 0; k < 4; k++){
      qp[k] = pack2(disv*q2[k].x, disv*q2[k].y);
      pp[k] = pack2(p2[k].x, p2[k].y);                 // RAW sum
      rp[k] = pack2(zinv*r2[k].x, zinv*r2[k].y);
    }
    *(uint4*)(Qb + o) = qo;
    *(uint4*)(Pb + o) = po;
    *(uint4*)(Rb + o) = ro;
    if (t == 0) b0[wv] = disv*qd;
  }
}

// ---------------- MFMA helpers, M=64 tile ----------------
__device__ __forceinline__ void stageB_async(u16* lds, const u16* __restrict__ w, int tid){
  int lane = tid & 63, wave = tid >> 6;
  #pragma unroll
  for (int i = 0; i < 8; i++){
    int cb = wave*64 + 256*i;
    async16(w + (size_t)(cb + lane)*8, lds + (size_t)cb*8);
  }
}
// A from registers (global fragment layout), B from LDS
__device__ __forceinline__ void mfma_regA(const short8 a[4], const u16* Bls,
                                          int lane, f32x4 acc[8]){
  int quad = lane >> 4, lr = lane & 15;
  #pragma unroll
  for (int ks = 0; ks < 4; ks++){
    int q = ks*4 + quad;
    short8 b[8];
    #pragma unroll
    for (int ct = 0; ct < 8; ct++)
      b[ct] = *(const short8*)(Bls + ((ct*16 + lr)*16 + (q ^ lr))*8);
    #pragma unroll
    for (int ct = 0; ct < 8; ct++)
      acc[ct] = __builtin_amdgcn_mfma_f32_16x16x32_bf16(a[ks], b[ct], acc[ct], 0, 0, 0);
  }
}

// ------- lin1 (R15): direct-reg A (f32 load + cvt), single LDS B stage -----
__global__ __launch_bounds__(256,3)
void k_gemm1(const float* __restrict__ A, const u16* __restrict__ Wb, const float* __restrict__ bias,
             const float* __restrict__ sm, float4* __restrict__ nd, u32* __restrict__ maxs,
             int Nn, u16* __restrict__ out)
{
  __shared__ __align__(16) u16 Bls[128*128];
  __shared__ float mred[4];
  int tid = threadIdx.x;
  int lane = tid & 63, wave = tid >> 6;
  int m0 = wave*16, mbase = blockIdx.x*64;
  int quad = lane >> 4, lr = lane & 15;
  stageB_async(Bls, Wb, tid);
  int arowi = mbase + m0 + lr;
  int arow = (arowi < Nn) ? arowi : (Nn - 1);
  short8 a[4];
  #pragma unroll
  for (int ks = 0; ks < 4; ks++){
    int q = ks*4 + quad;
    union { uint4 u; short8 s; } cv;
    cv.u = cvt8(A + (size_t)arow*HD + q*8);
    a[ks] = cv.s;
  }
  f32x4 acc[8];
  #pragma unroll
  for (int ct=0;ct<8;ct++) acc[ct] = (f32x4){0.f,0.f,0.f,0.f};
  __syncthreads();
  mfma_regA(a, Bls, lane, acc);
  #pragma unroll
  for (int ct=0;ct<8;ct++){
    float bc = bias[ct*16+lr];
    #pragma unroll
    for (int r=0;r<4;r++) acc[ct][r] = sane(acc[ct][r] + bc);
  }
  #pragma unroll
  for (int ct=0;ct<8;ct++){
    int c2 = ct*2 + (lr >> 3);
    #pragma unroll
    for (int r=0;r<4;r++){
      int grow = mbase + m0 + quad*4 + r;
      if (grow < Nn) out[(size_t)grow*HD + (c2 ^ (grow & 15))*8 + (lr & 7)] = f2b(acc[ct][r]);
    }
  }
  {
    const float* wsv = sm + 32;
    const float* wdv = sm + 416;
    float sp[4] = {0.f,0.f,0.f,0.f}, dp[4] = {0.f,0.f,0.f,0.f};
    #pragma unroll
    for (int ct=0;ct<8;ct++){
      float wsc = wsv[ct*16+lr], wdc = wdv[ct*16+lr];
      #pragma unroll
      for (int r=0;r<4;r++){
        sp[r] = fmaf(acc[ct][r], wsc, sp[r]);
        dp[r] = fmaf(acc[ct][r], wdc, dp[r]);
      }
    }
    #pragma unroll
    for (int off=1; off<16; off<<=1)
      #pragma unroll
      for (int r=0;r<4;r++){ sp[r] += __shfl_xor(sp[r], off); dp[r] += __shfl_xor(dp[r], off); }
    float ms = -3.4e38f;
    #pragma unroll
    for (int r=0;r<4;r++){
      int grow = mbase + m0 + quad*4 + r;
      if (grow < Nn){
        ms = fmaxf(ms, sp[r]);
        if (lr == 0) *(float2*)&nd[grow] = make_float2(sp[r], dp[r]);
      }
    }
    ms = fmaxf(ms, __shfl_xor(ms, 16));
    ms = fmaxf(ms, __shfl_xor(ms, 32));
    if (lane == 0) mred[wave] = ms;
    __syncthreads();
    if (tid == 0){
      float m = fmaxf(fmaxf(mred[0],mred[1]), fmaxf(mred[2],mred[3]));
      atomicMax(maxs + 0, fenc(m));
    }
  }
}

// ------- fused layer (R15): B dbuf staged one op ahead, A direct-reg.
// Pm/Gb derived in-register (A-fragment rows lane-uniform -> row scalars).
__global__ __launch_bounds__(256,2)
void k_layer3(const u16* __restrict__ X, const u16* __restrict__ Qb,
              const u16* __restrict__ Pb, const u16* __restrict__ Rb,
              float4* __restrict__ nd, const float* __restrict__ b0,
              const u16* __restrict__ wsb,
              const float* __restrict__ gcnB, const float* __restrict__ ginB,
              const float* __restrict__ sm, u32* __restrict__ maxs,
              int layer, int Nn, u16* __restrict__ out)
{
  __shared__ __align__(16) u16 Bls0[128*128];   // 32KB
  __shared__ __align__(16) u16 Bls1[128*128];   // 32KB
  __shared__ float mred[4];
  int tid = threadIdx.x;
  int lane = tid & 63, wave = tid >> 6;
  int m0 = wave*16, mbase = blockIdx.x*64;
  int quad = lane >> 4, lr = lane & 15;
  float w0 = sm[layer*4+0], w1 = sm[layer*4+1], w2 = sm[layer*4+2], w3 = sm[layer*4+3];
  float e1 = sm[17 + layer];
  const u16* gcnWb = wsb + (size_t)(1  + layer)*16384;
  const u16* WsWb  = wsb + (size_t)(4  + layer)*16384;
  const u16* WnWb  = wsb + (size_t)(7  + layer)*16384;
  const u16* ginWb = wsb + (size_t)(10 + layer)*16384;
  const u16* gatWb = wsb + (size_t)(13 + layer)*16384;

  int arowi = mbase + m0 + lr;
  int arow = (arowi < Nn) ? arowi : (Nn - 1);
  size_t abase = (size_t)arow * HD;
  int co[4];
  #pragma unroll
  for (int ks = 0; ks < 4; ks++) co[ks] = ((ks*4 + quad) ^ lr) * 8;
  float dvr = ((const float*)&nd[arow])[3];   // dinv of this lane's A row

  f32x4 mix[8];
  f32x4 acc[8];
  float b0r[4];
  #pragma unroll
  for (int r=0;r<4;r++){
    int grow = mbase + m0 + quad*4 + r;
    b0r[r] = (grow < Nn) ? b0[grow] : 0.f;
  }

  short8 aQ[4], aX[4], aP[4], aR[4], aT[4];
  // prologue
  stageB_async(Bls0, gcnWb, tid);
  #pragma unroll
  for (int ks=0;ks<4;ks++) aQ[ks] = *(const short8*)(Qb + abase + co[ks]);
  #pragma unroll
  for (int ks=0;ks<4;ks++) aX[ks] = *(const short8*)(X + abase + co[ks]);
  __syncthreads();                              // B0 resident

  // ---- op0: GCN (A=Qb, B=Bls0) ----
  stageB_async(Bls1, WsWb, tid);
  #pragma unroll
  for (int ct=0;ct<8;ct++) acc[ct] = (f32x4){0.f,0.f,0.f,0.f};
  mfma_regA(aQ, Bls0, lane, acc);
  #pragma unroll
  for (int ks=0;ks<4;ks++) aP[ks] = *(const short8*)(Pb + abase + co[ks]);
  {
    float gb[8];
    #pragma unroll
    for (int ct=0;ct<8;ct++) gb[ct] = gcnB[layer*HD + ct*16+lr];
    #pragma unroll
    for (int ct=0;ct<8;ct++)
      #pragma unroll
      for (int r=0;r<4;r++)
        mix[ct][r] = w0 * eluf(acc[ct][r] + b0r[r]*gb[ct]);
  }
  __syncthreads();                              // B1 resident; Bls0 free

  // ---- op1: SAGE self (A=X, B=Bls1) ----
  stageB_async(Bls0, WnWb, tid);
  #pragma unroll
  for (int ct=0;ct<8;ct++) acc[ct] = (f32x4){0.f,0.f,0.f,0.f};
  mfma_regA(aX, Bls1, lane, acc);
  #pragma unroll
  for (int ks=0;ks<4;ks++) aR[ks] = *(const short8*)(Rb + abase + co[ks]);
  __syncthreads();                              // B2 resident; Bls1 free

  // ---- op2: SAGE neighbor (A=dinv*Pb, B=Bls0), accumulate into same acc ----
  stageB_async(Bls1, ginWb, tid);
  #pragma unroll
  for (int ks=0;ks<4;ks++) aT[ks] = scale8(aP[ks], dvr);
  mfma_regA(aT, Bls0, lane, acc);
  #pragma unroll
  for (int ct=0;ct<8;ct++)
    #pragma unroll
    for (int r=0;r<4;r++)
      mix[ct][r] += w1 * eluf(acc[ct][r]);
  __syncthreads();                              // B3 resident; Bls0 free

  // ---- op3: GIN (A=(1+eps)X+Pb, B=Bls1) ----
  stageB_async(Bls0, gatWb, tid);
  #pragma unroll
  for (int ks=0;ks<4;ks++) aT[ks] = comb8(aX[ks], aP[ks], e1);
  #pragma unroll
  for (int ct=0;ct<8;ct++) acc[ct] = (f32x4){0.f,0.f,0.f,0.f};
  mfma_regA(aT, Bls1, lane, acc);
  {
    float gib[8];
    #pragma unroll
    for (int ct=0;ct<8;ct++) gib[ct] = ginB[layer*HD + ct*16+lr];
    #pragma unroll
    for (int ct=0;ct<8;ct++)
      #pragma unroll
      for (int r=0;r<4;r++)
        mix[ct][r] += w2 * eluf(acc[ct][r] + gib[ct]);
  }
  __syncthreads();                              // B4 resident

  // ---- op4: GAT (A=Rb, B=Bls0) ----
  #pragma unroll
  for (int ct=0;ct<8;ct++) acc[ct] = (f32x4){0.f,0.f,0.f,0.f};
  mfma_regA(aR, Bls0, lane, acc);
  #pragma unroll
  for (int ct=0;ct<8;ct++)
    #pragma unroll
    for (int r=0;r<4;r++)
      mix[ct][r] = sane(mix[ct][r] + w3 * eluf(acc[ct][r]));

  // ---- store swizzled ----
  #pragma unroll
  for (int ct=0;ct<8;ct++){
    int c2 = ct*2 + (lr >> 3);
    #pragma unroll
    for (int r=0;r<4;r++){
      int grow = mbase + m0 + quad*4 + r;
      if (grow < Nn) out[(size_t)grow*HD + (c2 ^ (grow & 15))*8 + (lr & 7)] = f2b(mix[ct][r]);
    }
  }
  // ---- epilogue: s,d for next layer + global maxS ----
  if (layer < 2){
    const float* wsv = sm + 32  + (layer+1)*128;
    const float* wdv = sm + 416 + (layer+1)*128;
    float sp[4] = {0.f,0.f,0.f,0.f}, dp[4] = {0.f,0.f,0.f,0.f};
    #pragma unroll
    for (int ct=0;ct<8;ct++){
      float wsc = wsv[ct*16+lr], wdc = wdv[ct*16+lr];
      #pragma unroll
      for (int r=0;r<4;r++){
        sp[r] = fmaf(mix[ct][r], wsc, sp[r]);
        dp[r] = fmaf(mix[ct][r], wdc, dp[r]);
      }
    }
    #pragma unroll
    for (int off=1; off<16; off<<=1)
      #pragma unroll
      for (int r=0;r<4;r++){ sp[r] += __shfl_xor(sp[r], off); dp[r] += __shfl_xor(dp[r], off); }
    float ms = -3.4e38f;
    #pragma unroll
    for (int r=0;r<4;r++){
      int grow = mbase + m0 + quad*4 + r;
      if (grow < Nn){
        ms = fmaxf(ms, sp[r]);
        if (lr == 0) *(float2*)&nd[grow] = make_float2(sp[r], dp[r]);
      }
    }
    ms = fmaxf(ms, __shfl_xor(ms, 16));
    ms = fmaxf(ms, __shfl_xor(ms, 32));
    if (lane == 0) mred[wave] = ms;
    __syncthreads();
    if (tid == 0){
      float m = fmaxf(fmaxf(mred[0],mred[1]), fmaxf(mred[2],mred[3]));
      atomicMax(maxs + layer + 1, fenc(m));
    }
  }
}

// ------- classifier with fused skip/layer-agg (inputs swizzled) ----------
// R16: vectorized LDS reads (uint4 x / float4 w) — 8x/4x fewer LDS ops.
__global__ __launch_bounds__(256)
void k_nc(const u16* __restrict__ X1, const u16* __restrict__ X2, const u16* __restrict__ X3,
          const float* __restrict__ W, const float* __restrict__ bias,
          const float* __restrict__ sm, int Nn, float* __restrict__ out)
{
  __shared__ __align__(16) u16 xs[32*136];
  __shared__ __align__(16) float wn[40*132];
  __shared__ float bs[40];
  int t = threadIdx.x;
  int nb = blockIdx.x*32;
  float c1 = sm[12], c2 = sm[13], la0 = sm[14], la1 = sm[15], la2 = sm[16];
  #pragma unroll
  for (int i = 0; i < 2; i++){
    int chunk = t + 256*i;
    int r = chunk >> 4, c = chunk & 15;
    uint4 v = {0u,0u,0u,0u};
    int gr = nb + r;
    if (gr < Nn){
      size_t o = (size_t)gr*HD + ((c ^ (gr & 15))*8);
      uint4 u1 = *(const uint4*)(X1 + o);
      uint4 u2 = *(const uint4*)(X2 + o);
      uint4 u3 = *(const uint4*)(X3 + o);
      u32* u1p = (u32*)&u1; u32* u2p = (u32*)&u2; u32* u3p = (u32*)&u3; u32* vp = (u32*)&v;
      #pragma unroll
      for (int k = 0; k < 4; k++){
        float o0, o1;
        {
          float a1 = lo2f(u1p[k]), a2 = lo2f(u2p[k]), a3 = lo2f(u3p[k]);
          float t0 = a3, t1 = c1*a1, t2 = c2*a2;
          float smm = t0 + t1 + t2;
          float mx = fmaxf(fmaxf(t0,t1),t2);
          o0 = la0*reluf(mx) + la1*reluf(smm*(1.f/3.f)) + la2*reluf(smm);
        }
        {
          float a1 = hi2f(u1p[k]), a2 = hi2f(u2p[k]), a3 = hi2f(u3p[k]);
          float t0 = a3, t1 = c1*a1, t2 = c2*a2;
          float smm = t0 + t1 + t2;
          float mx = fmaxf(fmaxf(t0,t1),t2);
          o1 = la0*reluf(mx) + la1*reluf(smm*(1.f/3.f)) + la2*reluf(smm);
        }
        vp[k] = pack2(sane(o0), sane(o1));
      }
    }
    *(uint4*)(xs + r*136 + c*8) = v;
  }
  #pragma unroll
  for (int i = 0; i < 5; i++){
    int chunk = t + 256*i;
    int r = chunk >> 5, c = chunk & 31;
    *(float4*)(wn + r*132 + c*4) = *(const float4*)(W + r*HD + c*4);
  }
  if (t < 40) bs[t] = bias[t];
  __syncthreads();
  int nl = t >> 3, cg = t & 7;
  float acc[5];
  #pragma unroll
  for (int j = 0; j < 5; j++) acc[j] = bs[cg + 8*j];
  for (int k0 = 0; k0 < 128; k0 += 8){
    uint4 xv = *(const uint4*)(xs + nl*136 + k0);
    const u32* xp = (const u32*)&xv;
    float xf[8];
    #pragma unroll
    for (int q = 0; q < 4; q++){ xf[2*q] = lo2f(xp[q]); xf[2*q+1] = hi2f(xp[q]); }
    #pragma unroll
    for (int j = 0; j < 5; j++){
      const float* wr = wn + (cg + 8*j)*132 + k0;
      float4 w0 = *(const float4*)(wr);
      float4 w1 = *(const float4*)(wr + 4);
      acc[j] = fmaf(xf[0], w0.x, acc[j]);
      acc[j] = fmaf(xf[1], w0.y, acc[j]);
      acc[j] = fmaf(xf[2], w0.z, acc[j]);
      acc[j] = fmaf(xf[3], w0.w, acc[j]);
      acc[j] = fmaf(xf[4], w1.x, acc[j]);
      acc[j] = fmaf(xf[5], w1.y, acc[j]);
      acc[j] = fmaf(xf[6], w1.z, acc[j]);
      acc[j] = fmaf(xf[7], w1.w, acc[j]);
    }
  }
  int gr = nb + nl;
  if (gr < Nn){
    #pragma unroll
    for (int j = 0; j < 5; j++)
      out[(size_t)gr*40 + cg + 8*j] = sane(acc[j]);
  }
}

// ---------------- host ----------------
extern "C" void kernel_launch(void* const* d_in, const int* in_sizes, int n_in,
                              void* d_out, int out_size, void* d_ws, size_t ws_size,
                              hipStream_t stream)
{
  (void)n_in; (void)out_size; (void)ws_size;
  const int N = in_sizes[0] / HD;
  const int E = in_sizes[1] / 2;
  const float* x      = (const float*)d_in[0];
  const int*   ei     = (const int*)d_in[1];
  const float* na_a   = (const float*)d_in[2];
  const float* sc_a   = (const float*)d_in[3];
  const float* la_a   = (const float*)d_in[4];
  const float* lin1W  = (const float*)d_in[5];
  const float* lin1b  = (const float*)d_in[6];
  const float* gcnW   = (const float*)d_in[7];
  const float* gcnB   = (const float*)d_in[8];
  const float* sageWs = (const float*)d_in[9];
  const float* sageWn = (const float*)d_in[10];
  const float* ginW   = (const float*)d_in[11];
  const float* ginB   = (const float*)d_in[12];
  const float* ginE   = (const float*)d_in[13];
  const float* gatW   = (const float*)d_in[14];
  const float* gatAs  = (const float*)d_in[15];
  const float* gatAd  = (const float*)d_in[16];
  const float* ncW    = (const float*)d_in[17];
  const float* ncB    = (const float*)d_in[18];

  char* base = (char*)d_ws;
  size_t off = 0;
  auto alloc = [&](size_t b) -> void* {
    void* p = base + off;
    off += (b + 255) & ~(size_t)255;
    return p;
  };
  const int NB  = (N + 1023) / 1024;       // 1024-node scan blocks
  const int B   = (N + 255) >> 8;          // 256-node edge buckets (<=256)
  const int nbe = (E + ETILE - 1) / ETILE; // edge tiles
  float*  smalls = (float*)alloc(4096);
  u32*    maxs   = (u32*)alloc(256);
  int*    cnt    = (int*)alloc((size_t)N*4);
  int*    rowptr = (int*)alloc(((size_t)N+1)*4);
  int*    bsum   = (int*)alloc(4096);
  int*    boffs  = (int*)alloc(4096);
  int*    bh     = (int*)alloc((size_t)NB*256*4);
  int*    perm   = (int*)alloc((size_t)N*4);
  int*    eh     = (int*)alloc((size_t)nbe*256*4);
  int*    btot   = (int*)alloc(1024);
  int*    bbase  = (int*)alloc(1040);
  float4* nd     = (float4*)alloc((size_t)N*16);
  float*  b0     = (float*)alloc((size_t)N*4);
  int*    csr    = (int*)alloc((size_t)E*4);
  u16*    wsb    = (u16*)alloc((size_t)16*16384*2);
  u16*    xh     = (u16*)alloc((size_t)N*HD*2);
  u16*    x1     = (u16*)alloc((size_t)N*HD*2);
  u16*    x2     = (u16*)alloc((size_t)N*HD*2);
  u16*    Qb     = (u16*)alloc((size_t)N*HD*2);
  u16*    Pb     = (u16*)alloc((size_t)N*HD*2);
  u16*    Rb     = (u16*)alloc((size_t)N*HD*2);
  // ebuf (E*8 = 6.4MB) aliases Qb (12.8MB): k_bfill completes before k_agg
  // first writes Qb (stream-ordered), so no overlap in lifetime.
  int2*   ebuf   = (int2*)Qb;

  // wcvt + small precompute (merged)
  k_wcvt<<<128,256,0,stream>>>(lin1W, gcnW, sageWs, sageWn, ginW, gatW, wsb,
                               na_a, sc_a, la_a, gatAs, gatAd, ginE, smalls, maxs);
  // ---- CSR build: bucketed counting sort, zero global fine-grained atomics
  k_ehist<<<nbe,256,0,stream>>>(ei, E, eh);
  k_escan<<<B,256,0,stream>>>(eh, nbe, btot);
  k_bscan<<<1,256,0,stream>>>(btot, B, E, bbase);
  k_escat<<<nbe,256,0,stream>>>(ei, E, B, eh, bbase, ebuf);
  k_bcount<<<B,256,0,stream>>>(ebuf, bbase, N, cnt);
  // ---- merged node preprocessing (R16): 6 launches -> 3
  k_scanhist<<<NB,256,0,stream>>>(cnt, N, bsum, bh);
  k_scan2h<<<1,1024,0,stream>>>(bsum, NB, boffs, rowptr, N, bh);
  k_scan3p<<<NB,256,0,stream>>>(cnt, boffs, N, rowptr, nd, bh, perm);
  k_bfill<<<B,256,0,stream>>>(ebuf, bbase, rowptr, N, csr);
  int gbl64 = (N + 63)/64;
  k_gemm1<<<gbl64,256,0,stream>>>(x, wsb, lin1b, smalls, nd, maxs, N, xh);
  const u16* xc = xh;
  u16* outs[3] = {x1, x2, xh};
  int abl = (N + 15)/16;
  for (int l = 0; l < 3; l++){
    k_agg<<<abl,256,0,stream>>>(xc, rowptr, csr, perm, nd, smalls, maxs, l, N, Qb, Pb, Rb, b0);
    k_layer3<<<gbl64,256,0,stream>>>(xc, Qb, Pb, Rb, nd, b0, wsb,
                                     gcnB, ginB, smalls, maxs, l, N, outs[l]);
    xc = outs[l];
  }
  int ncbl = (N + 31)/32;
  k_nc<<<ncbl,256,0,stream>>>(x1, x2, xh, ncW, ncB, smalls, N, (float*)d_out);
}